// Round 9
// baseline (868.325 us; speedup 1.0000x reference)
//
#include <hip/hip_runtime.h>
#include <math.h>

#define NIMG 8
#define CIN  512
#define HF   50
#define WF   64
#define HW   3200
#define NA   9
#define KPER 28800   /* HW*NA per image */
#define PRE  6000
#define POST 300

#define WHT_ELEMS  32768     /* 512*64 */

/* sorted-candidate padding: 94 words * 64 = 6016 rows */
#define NW    94             /* u64 words per mask row */
#define NCAP  6016           /* padded candidate count */
#define NTRI  4465           /* NW*(NW+1)/2 upper-tri blocks */

/* k_select block size: 4 waves -> cheap barriers in the 91-stage bitonic */
#define SELT  256

/* padded NHWC f16 input: rows 52 (row p holds x row p-1; p=0,51 zero),
   cols 66 (col w' holds x col w'-1; w'=0,65 zero), ci contiguous. */
#define XTROWS 52
#define XTCOLS 66
#define XT_ELEMS ((size_t)NIMG * XTROWS * XTCOLS * CIN)   /* 14,057,472 */
#define XT_BYTES (XT_ELEMS * 2)                            /* 28,114,944 */

/* packed weights: [sp2][cob4][tap9][ks16][4096 f16] in LDS-physical tile order */
#define WPK_ELEMS ((size_t)2 * 4 * 9 * 16 * 4096)          /* 4,718,592 */
#define WPK_HALF  (4 * 9 * 16 * 4096)                      /* 2,359,296 */

/* scaling: x' = x*2^8, w' = w*2^14; acc scale 2^22 undone in epilogue */
#define SCALE_X 256.0f
#define SCALE_W 16384.0f
#define INV_SCALE (1.0f / 4194304.0f)   /* 2^-22 */

/* prep_all block ranges */
#define PB_XT   1600
#define PB_HALO 64
#define PB_WPK  288
#define PB_PH   16
#define PB_TOT  (PB_XT + PB_HALO + PB_WPK + PB_PH)   /* 1968 */

/* halo vec8 counts */
#define HALO_VPI 14848        /* vec8 per image per array */
#define HALO_TOT (NIMG * HALO_VPI)   /* 118,784 */

typedef _Float16 f16x8 __attribute__((ext_vector_type(8)));
typedef float f32x4  __attribute__((ext_vector_type(4)));
typedef unsigned short u16x8 __attribute__((ext_vector_type(8)));
typedef unsigned long long u64;

// Base anchors (x1,y1,x2,y2) computed in double, rounded to f32 (matches np.float32 cast)
__constant__ float BASEA[9][4] = {
  {-82.509667991878083f, -37.254833995939042f,  98.509667991878083f,  53.254833995939042f},
  {-173.01933598375617f, -82.509667991878083f, 189.01933598375617f,   98.509667991878083f},
  {-354.03867196751233f, -173.01933598375617f, 370.03867196751233f,  189.01933598375617f},
  { -56.0f,  -56.0f,  72.0f,  72.0f},
  {-120.0f, -120.0f, 136.0f, 136.0f},
  {-248.0f, -248.0f, 264.0f, 264.0f},
  {-37.254833995939042f, -82.509667991878083f,  53.254833995939042f,  98.509667991878083f},
  {-82.509667991878083f, -173.01933598375617f,  98.509667991878083f, 189.01933598375617f},
  {-173.01933598375617f, -354.03867196751233f, 189.01933598375617f,  370.03867196751233f},
};

__device__ __forceinline__ unsigned int ordf(float f) {
  unsigned int u = __float_as_uint(f);
  return (u & 0x80000000u) ? ~u : (u | 0x80000000u);
}

__device__ __forceinline__ unsigned short f2h(float f) {
  union { _Float16 h; unsigned short u; } cv;
  cv.h = (_Float16)f;             /* v_cvt_f16_f32, RNE */
  return cv.u;
}
__device__ __forceinline__ float h2f(unsigned short u) {
  union { _Float16 h; unsigned short u; } cv;
  cv.u = u;
  return (float)cv.h;
}

// ---------------------------------------------------------------------------
// P: fused prep (validated r4).
// ---------------------------------------------------------------------------
__global__ __launch_bounds__(256) void k_prep_all(
    const float4* __restrict__ x4,
    const float* __restrict__ w1,
    const float* __restrict__ wc, const float* __restrict__ bc,
    const float* __restrict__ wb, const float* __restrict__ bb,
    unsigned short* __restrict__ xh, unsigned short* __restrict__ xl,
    unsigned short* __restrict__ wpk,
    float* __restrict__ WHT2, float* __restrict__ bh) {
  __shared__ float tile[128][65];
  const int blk = blockIdx.x;
  const int t = threadIdx.x;

  if (blk < PB_XT) {
    const int cic = blk & 3;
    const int rest = blk >> 2;
    const int hrow = rest % 50;
    const int n = rest / 50;
#pragma unroll
    for (int jj = 0; jj < 8; ++jj) {
      const int e = t + 256 * jj;              /* 0..2047 */
      const int row = e >> 4, c4 = e & 15;
      const float4 v = x4[(((size_t)(n * CIN + cic * 128 + row) * HF + hrow) << 4) + c4];
      tile[row][c4 * 4 + 0] = v.x;
      tile[row][c4 * 4 + 1] = v.y;
      tile[row][c4 * 4 + 2] = v.z;
      tile[row][c4 * 4 + 3] = v.w;
    }
    __syncthreads();
#pragma unroll
    for (int jj = 0; jj < 4; ++jj) {
      const int e = t + 256 * jj;              /* 0..1023 */
      const int w = e >> 4, c8 = e & 15;
      const size_t base = ((size_t)((n * XTROWS + (hrow + 1)) * XTCOLS) + (w + 1)) * CIN
                          + cic * 128 + c8 * 8;
      u16x8 hv, lv;
#pragma unroll
      for (int u = 0; u < 8; ++u) {
        const float g = tile[c8 * 8 + u][w] * SCALE_X;
        const unsigned short hh = f2h(g);
        hv[u] = (short)hh;
        lv[u] = (short)f2h(g - h2f(hh));
      }
      *reinterpret_cast<u16x8*>(xh + base) = hv;
      *reinterpret_cast<u16x8*>(xl + base) = lv;
    }
  } else if (blk < PB_XT + PB_HALO) {
    const u16x8 z = {0, 0, 0, 0, 0, 0, 0, 0};
    const int tid = (blk - PB_XT) * 256 + t;   /* 0..16383 */
    for (int v = tid; v < HALO_TOT; v += PB_HALO * 256) {
      const int n = v / HALO_VPI;
      const int r = v - n * HALO_VPI;
      int row, col, v8;
      if (r < 8448) {                       /* rows 0,51 : 2*66*64 */
        row = (r < 4224) ? 0 : 51;
        const int r2 = (r < 4224) ? r : r - 4224;
        col = r2 >> 6;
        v8 = r2 & 63;
      } else {                              /* rows 1..50, cols 0/65 */
        const int q = r - 8448;             /* 0..6399 */
        row = 1 + (q >> 7);
        const int rr = q & 127;
        col = (rr >= 64) ? 65 : 0;
        v8 = rr & 63;
      }
      const size_t off = ((size_t)((n * XTROWS + row) * XTCOLS) + col) * CIN + v8 * 8;
      *reinterpret_cast<u16x8*>(xh + off) = z;
      *reinterpret_cast<u16x8*>(xl + off) = z;
    }
  } else if (blk < PB_XT + PB_HALO + PB_WPK) {
    const int tot = (int)WPK_ELEMS;
    const int tid = (blk - PB_XT - PB_HALO) * 256 + t;
    for (int idx = tid; idx < tot; idx += PB_WPK * 256) {
      const int i = idx & 4095;
      int rest = idx >> 12;
      const int ks = rest & 15; rest >>= 4;
      const int tap = rest % 9; rest /= 9;
      const int cob = rest & 3;
      const int sp = rest >> 2;
      const int col = i >> 5;
      const int slotp = (i >> 3) & 3;
      const int j = i & 7;
      const int s = slotp ^ ((col >> 1) & 3);
      const int ci = ks * 32 + s * 8 + j;
      const int co = cob * 128 + col;
      const float g = w1[((size_t)co * CIN + ci) * 9 + tap] * SCALE_W;
      const unsigned short hh = f2h(g);
      wpk[idx] = sp ? f2h(g - h2f(hh)) : hh;
    }
  } else {
    const int TOT = WHT_ELEMS + 64;
    const int tid = (blk - PB_XT - PB_HALO - PB_WPK) * 256 + t;
    for (int idx = tid; idx < TOT; idx += PB_PH * 256) {
      if (idx < WHT_ELEMS) {
        int r = idx & 3;
        int o = (idx >> 2) & 63;
        int c = (idx >> 8) * 4 + r;
        float v = 0.0f;
        if (o < 18) v = wc[(size_t)o * CIN + c];
        else if (o < 54) v = wb[(size_t)(o - 18) * CIN + c];
        WHT2[idx] = v;
      } else {
        int o = idx - WHT_ELEMS;
        float v = 0.0f;
        if (o < 18) v = bc[o];
        else if (o < 54) v = bb[o - 18];
        bh[o] = v;
      }
    }
  }
}

// ---------------------------------------------------------------------------
// K1: 3x3 conv 512->512 as implicit GEMM on MFMA, fp32-emulated via scaled-f16
// hi/lo split (Ah*Bh + Ah*Bl + Al*Bh).  Validated r2; XCD swizzle r4.
// At the 2-barrier structural ceiling (39% dense peak, guide m97 reference).
// ---------------------------------------------------------------------------
#define GLDS(gp, lp) __builtin_amdgcn_global_load_lds( \
    (const __attribute__((address_space(1))) unsigned int*)(gp), \
    (__attribute__((address_space(3))) unsigned int*)(lp), 16, 0, 0)

__global__ __launch_bounds__(256, 2) void k_convmfma(
    const unsigned short* __restrict__ xh,
    const unsigned short* __restrict__ xl,
    const unsigned short* __restrict__ wpk,
    const float* __restrict__ b1,
    float* __restrict__ feat) {
  __shared__ unsigned short lds[2][4][4096];   /* 64 KiB: [buf][Ah,Al,Bh,Bl] */

  const int raw = blockIdx.x;
  const int xcd = raw & 7;
  const int idx = raw >> 3;          /* 0..99 */
  const int cob = xcd >> 1;          /* 0..3 */
  const int pb  = (xcd & 1) * 100 + idx;   /* 0..199 : n*25 + hb */

  const int n   = pb / 25;
  const int h0  = (pb - n * 25) * 2;
  const int t   = threadIdx.x;
  const int wid = t >> 6;
  const int l   = t & 63;
  const int wm  = wid >> 1;          /* wave M index (co) */
  const int wn  = wid & 1;           /* wave N index (pos row) */

  const int colp = l >> 2;                               /* w within 16-col group */
  const int sB = (((l & 3) ^ ((l >> 3) & 3)) << 3);      /* swizzled k-slot elem off */
  const unsigned short* xsrc = (wid == 3) ? xl : xh;
  const size_t wA_base = (size_t)(wid & 1) * WPK_HALF;

  const int fr = l & 15;
  const int fq = l >> 4;
  const int slotr = ((fq ^ ((fr >> 1) & 3)) << 4);       /* swizzled 16B slot (bytes) */

  f32x4 acc[4][4] = {};

  auto stage = [&](int sbuf, int ti) {
    const int ks  = ti / 9;          /* ci chunk  (slow) */
    const int tap = ti - ks * 9;     /* 3x3 tap   (fast: L2 reuse of x rows) */
    if (wid < 2) {
      const unsigned short* gp = wpk + wA_base
          + ((size_t)((cob * 9 + tap) * 16 + ks) << 12) + l * 8;
      unsigned short* lp = &lds[sbuf][wid][0];
#pragma unroll
      for (int q = 0; q < 8; ++q)
        GLDS(gp + q * 512, lp + q * 512);
    } else {
      const int ky = (tap * 11) >> 5;       /* tap/3 for 0..8 */
      const int kx = tap - ky * 3;
      const size_t ebase = ((size_t)((n * XTROWS + h0 + ky) * XTCOLS + kx + colp) << 9)
                           + ks * 32 + sB;
      unsigned short* lp = &lds[sbuf][wid][0];
#pragma unroll
      for (int q = 0; q < 8; ++q)
        GLDS(xsrc + ebase + ((size_t)(((q >> 2) * XTCOLS + (q & 3) * 16)) << 9),
             lp + q * 512);
    }
  };

  stage(0, 0);
  __syncthreads();

  int buf = 0;
  for (int ti = 0; ti < 144; ++ti) {
    if (ti < 143) stage(buf ^ 1, ti + 1);   /* issue next-step loads first */

    f16x8 ah[4], al[4], bhf[4], blf[4];
#pragma unroll
    for (int mi = 0; mi < 4; ++mi) {
      const int off = (((wm << 6) + (mi << 4) + fr) << 6) + slotr;
      ah[mi] = *(const f16x8*)((const char*)&lds[buf][0][0] + off);
      al[mi] = *(const f16x8*)((const char*)&lds[buf][1][0] + off);
    }
#pragma unroll
    for (int ni = 0; ni < 4; ++ni) {
      const int off = (((wn << 6) + (ni << 4) + fr) << 6) + slotr;
      bhf[ni] = *(const f16x8*)((const char*)&lds[buf][2][0] + off);
      blf[ni] = *(const f16x8*)((const char*)&lds[buf][3][0] + off);
    }
#pragma unroll
    for (int mi = 0; mi < 4; ++mi)
#pragma unroll
      for (int ni = 0; ni < 4; ++ni) {
        acc[mi][ni] = __builtin_amdgcn_mfma_f32_16x16x32_f16(ah[mi], bhf[ni], acc[mi][ni], 0, 0, 0);
        acc[mi][ni] = __builtin_amdgcn_mfma_f32_16x16x32_f16(ah[mi], blf[ni], acc[mi][ni], 0, 0, 0);
        acc[mi][ni] = __builtin_amdgcn_mfma_f32_16x16x32_f16(al[mi], bhf[ni], acc[mi][ni], 0, 0, 0);
      }
    __syncthreads();                        /* drains vmcnt(0): next buf ready */
    buf ^= 1;
  }

  const int h = h0 + wn;
#pragma unroll
  for (int mi = 0; mi < 4; ++mi) {
    const int co = (cob << 7) + (wm << 6) + (mi << 4) + (fq << 2);
    const float4 bias = *(const float4*)&b1[co];
#pragma unroll
    for (int ni = 0; ni < 4; ++ni) {
      const int w = (ni << 4) + fr;
      float4 v;
      v.x = fmaxf(fmaf(acc[mi][ni][0], INV_SCALE, bias.x), 0.0f);
      v.y = fmaxf(fmaf(acc[mi][ni][1], INV_SCALE, bias.y), 0.0f);
      v.z = fmaxf(fmaf(acc[mi][ni][2], INV_SCALE, bias.z), 0.0f);
      v.w = fmaxf(fmaf(acc[mi][ni][3], INV_SCALE, bias.w), 0.0f);
      *(float4*)(feat + (((size_t)n * HW + h * WF + w) << 9) + co) = v;
    }
  }
}

// ---------------------------------------------------------------------------
// K2: 1x1 heads + softmax-fg + box decode + clip + min-size filter.
// (identical numerics to validated r2 kernel; r7: float4 feat staging)
// ---------------------------------------------------------------------------
__global__ __launch_bounds__(256) void k_head(const float* __restrict__ feat,
                                              const float* __restrict__ WHT2,
                                              const float* __restrict__ bh,
                                              float* __restrict__ scores,
                                              float4* __restrict__ boxes) {
  __shared__ float fsh[16][512];
  __shared__ float vsh[16][64];
  const int t = threadIdx.x;
  const int wvid = t >> 6;
  const int o = t & 63;
  const int pos0 = blockIdx.x * 16;

  {
    const float4* fsrc = reinterpret_cast<const float4*>(feat + ((size_t)pos0 << 9));
    float4* fdst = reinterpret_cast<float4*>(&fsh[0][0]);
#pragma unroll
    for (int i = 0; i < 8; ++i) fdst[t + 256 * i] = fsrc[t + 256 * i];
  }
  __syncthreads();

  {
    const int p0 = wvid * 4;
    float a0 = 0.f, a1 = 0.f, a2 = 0.f, a3 = 0.f;
    const float4* wp = reinterpret_cast<const float4*>(WHT2);
    const float4* f0 = reinterpret_cast<const float4*>(&fsh[p0 + 0][0]);
    const float4* f1 = reinterpret_cast<const float4*>(&fsh[p0 + 1][0]);
    const float4* f2 = reinterpret_cast<const float4*>(&fsh[p0 + 2][0]);
    const float4* f3 = reinterpret_cast<const float4*>(&fsh[p0 + 3][0]);
#pragma unroll 4
    for (int c4 = 0; c4 < 128; ++c4) {
      float4 w4 = wp[c4 * 64 + o];
      float4 v;
      v = f0[c4];
      a0 = fmaf(w4.x, v.x, a0); a0 = fmaf(w4.y, v.y, a0);
      a0 = fmaf(w4.z, v.z, a0); a0 = fmaf(w4.w, v.w, a0);
      v = f1[c4];
      a1 = fmaf(w4.x, v.x, a1); a1 = fmaf(w4.y, v.y, a1);
      a1 = fmaf(w4.z, v.z, a1); a1 = fmaf(w4.w, v.w, a1);
      v = f2[c4];
      a2 = fmaf(w4.x, v.x, a2); a2 = fmaf(w4.y, v.y, a2);
      a2 = fmaf(w4.z, v.z, a2); a2 = fmaf(w4.w, v.w, a2);
      v = f3[c4];
      a3 = fmaf(w4.x, v.x, a3); a3 = fmaf(w4.y, v.y, a3);
      a3 = fmaf(w4.z, v.z, a3); a3 = fmaf(w4.w, v.w, a3);
    }
    float bv = bh[o];
    vsh[p0 + 0][o] = a0 + bv;
    vsh[p0 + 1][o] = a1 + bv;
    vsh[p0 + 2][o] = a2 + bv;
    vsh[p0 + 3][o] = a3 + bv;
  }
  __syncthreads();

  if (t < 144) {
    const int p2 = t / 9, a = t % 9;
    const int pos = pos0 + p2;
    const int n = pos / HW;
    const int r = pos - n * HW;
    const int ph = r >> 6;
    const int pw = r & 63;

    float l0 = vsh[p2][a * 2];
    float l1 = vsh[p2][a * 2 + 1];
    float m  = fmaxf(l0, l1);
    float e0 = (float)exp((double)__fsub_rn(l0, m));
    float e1 = (float)exp((double)__fsub_rn(l1, m));
    float fg = __fdiv_rn(e1, __fadd_rn(e0, e1));

    float d0 = vsh[p2][18 + a * 4 + 0];
    float d1 = vsh[p2][18 + a * 4 + 1];
    float d2 = vsh[p2][18 + a * 4 + 2];
    float d3 = vsh[p2][18 + a * 4 + 3];

    float sx = (float)(pw * 16);
    float sy = (float)(ph * 16);
    float ax1 = __fadd_rn(BASEA[a][0], sx);
    float ay1 = __fadd_rn(BASEA[a][1], sy);
    float ax2 = __fadd_rn(BASEA[a][2], sx);
    float ay2 = __fadd_rn(BASEA[a][3], sy);
    float aw = __fsub_rn(ax2, ax1);
    float ah = __fsub_rn(ay2, ay1);
    float acx = __fadd_rn(ax1, __fmul_rn(0.5f, aw));
    float acy = __fadd_rn(ay1, __fmul_rn(0.5f, ah));
    float cx = __fadd_rn(__fmul_rn(d0, aw), acx);
    float cy = __fadd_rn(__fmul_rn(d1, ah), acy);
    float pwd = __fmul_rn((float)exp((double)d2), aw);
    float phd = __fmul_rn((float)exp((double)d3), ah);
    float x1 = __fsub_rn(cx, __fmul_rn(0.5f, pwd));
    float y1 = __fsub_rn(cy, __fmul_rn(0.5f, phd));
    float x2 = __fadd_rn(cx, __fmul_rn(0.5f, pwd));
    float y2 = __fadd_rn(cy, __fmul_rn(0.5f, phd));
    x1 = fminf(fmaxf(x1, 0.0f), 1024.0f);
    x2 = fminf(fmaxf(x2, 0.0f), 1024.0f);
    y1 = fminf(fmaxf(y1, 0.0f), 800.0f);
    y2 = fminf(fmaxf(y2, 0.0f), 800.0f);
    float wsz = __fsub_rn(x2, x1);
    float hsz = __fsub_rn(y2, y1);
    float sc = (wsz >= 16.0f && hsz >= 16.0f) ? fg : -__builtin_huge_valf();

    const int idx = n * KPER + r * NA + a;
    scores[idx] = sc;
    boxes[idx] = make_float4(x1, y1, x2, y2);
  }
}

// ---------------------------------------------------------------------------
// K3 (merged topk + sort; r9: 256 threads / 4 waves).  Identical algorithm &
// outputs to the validated 1024-thread version; only the thread->work mapping
// changed.  Mechanism: 91 bitonic-stage barriers cost ~0.55us each at 16
// waves (r5 measurement) but ~0.1us at 4 waves.
// ---------------------------------------------------------------------------
__global__ __launch_bounds__(SELT) void k_select(const float* __restrict__ scores,
                                                 const float4* __restrict__ boxes,
                                                 float4* __restrict__ sbox,
                                                 u64* __restrict__ valid) {
  __shared__ u64 sk[8192];
  __shared__ unsigned int whist[4][264];   /* per-wave, 264-stride staggers banks */
  __shared__ unsigned int histT[256];
  __shared__ unsigned int sh_selB, sh_ngt, sh_binc, sh_num;
  const int n = blockIdx.x;
  const int t = threadIdx.x;
  const int wv = t >> 6;
  const float* sc = scores + (size_t)n * KPER;
  const float4* sc4 = reinterpret_cast<const float4*>(sc);

  for (int e = t; e < 8192; e += SELT) sk[e] = 0ull;   /* pad + slots */

  unsigned int prefix = 0, prefMask = 0, ngt = 0, neq = 0;
  for (int shift = 24; shift >= 0; shift -= 8) {
    for (int e = t; e < 4 * 264; e += SELT) (&whist[0][0])[e] = 0u;
    __syncthreads();
    for (int i4 = t; i4 < KPER / 4; i4 += SELT) {
      const float4 v = sc4[i4];
      unsigned int u;
      u = ordf(v.x); if ((u & prefMask) == prefix) atomicAdd(&whist[wv][(u >> shift) & 255], 1u);
      u = ordf(v.y); if ((u & prefMask) == prefix) atomicAdd(&whist[wv][(u >> shift) & 255], 1u);
      u = ordf(v.z); if ((u & prefMask) == prefix) atomicAdd(&whist[wv][(u >> shift) & 255], 1u);
      u = ordf(v.w); if ((u & prefMask) == prefix) atomicAdd(&whist[wv][(u >> shift) & 255], 1u);
    }
    __syncthreads();
    {
      unsigned int s = 0;
#pragma unroll
      for (int w = 0; w < 4; ++w) s += whist[w][t];
      histT[t] = s;
    }
    __syncthreads();
    if (t == 0) {
      unsigned int cnt = ngt;
      for (int b = 255; b >= 0; --b) {
        unsigned int c = histT[b];
        if (cnt + c >= (unsigned)PRE) { sh_selB = (unsigned)b; sh_ngt = cnt; sh_binc = c; break; }
        cnt += c;
      }
    }
    __syncthreads();
    prefix |= (sh_selB << shift);
    prefMask |= (0xFFu << shift);
    ngt = sh_ngt;
    neq = sh_binc;
    __syncthreads();
  }
  const unsigned int T = prefix;
  const unsigned int needed = (unsigned)PRE - ngt;
  unsigned int J = 0xFFFFFFFFu;
  if (needed < neq) {
    histT[t] = 0;
    __syncthreads();
    for (int i = t; i < KPER; i += SELT)
      if (ordf(sc[i]) == T) atomicAdd(&histT[i >> 7], 1u);
    __syncthreads();
    if (t == 0) {
      unsigned int cnt = 0;
      for (int b = 0; b < 256; ++b) {
        unsigned int c = histT[b];
        if (cnt + c >= needed) { sh_selB = (unsigned)b; sh_ngt = needed - cnt; break; }
        cnt += c;
      }
    }
    __syncthreads();
    const unsigned int selH = sh_selB;
    const unsigned int needLow = sh_ngt;
    __syncthreads();
    if (t < 128) histT[t] = 0;
    __syncthreads();
    for (int i = t; i < KPER; i += SELT)
      if (ordf(sc[i]) == T && ((unsigned)(i >> 7)) == selH) atomicAdd(&histT[i & 127], 1u);
    __syncthreads();
    if (t == 0) {
      unsigned int cnt = 0;
      for (int b = 0; b < 128; ++b) {
        unsigned int c = histT[b];
        if (cnt + c >= needLow) { sh_selB = (selH << 7) | (unsigned)b; break; }
        cnt += c;
      }
    }
    __syncthreads();
    J = sh_selB;
  }

  if (t == 0) sh_num = 0;
  __syncthreads();
  for (int i4 = t; i4 < KPER / 4; i4 += SELT) {
    const float4 v = sc4[i4];
    const float vv[4] = {v.x, v.y, v.z, v.w};
#pragma unroll
    for (int c = 0; c < 4; ++c) {
      const int i = i4 * 4 + c;
      unsigned int u = ordf(vv[c]);
      bool in = (u > T) || (u == T && (unsigned)i <= J);
      if (in) {
        unsigned int p = atomicAdd(&sh_num, 1u);
        sk[p] = (((u64)u) << 32) | (u64)(~(unsigned int)i);
      }
    }
  }
  __syncthreads();

  /* bitonic sort descending, 8192 elems (pad 0 sorts to tail) */
  for (int k = 2; k <= 8192; k <<= 1) {
    for (int j = k >> 1; j > 0; j >>= 1) {
      for (int p = t; p < 4096; p += SELT) {
        const int i = ((p & ~(j - 1)) << 1) | (p & (j - 1));
        const int ip = i | j;
        u64 a = sk[i], b = sk[ip];
        const bool desc = ((i & k) == 0);
        if ((a < b) == desc) { sk[i] = b; sk[ip] = a; }
      }
      __syncthreads();
    }
  }

  /* gather sorted boxes + valid bitmap */
  for (int e = t; e < NCAP; e += SELT) {
    float4 bx = make_float4(0.f, 0.f, 0.f, 0.f);
    if (e < PRE) {
      unsigned idx = ~(unsigned)(sk[e] & 0xFFFFFFFFull);
      bx = boxes[(size_t)n * KPER + idx];
    }
    sbox[(size_t)n * NCAP + e] = bx;
  }
  if (t < 128) {
    u64 w = 0;
    if (t < NW) {
      for (int b = 0; b < 64; ++b) {
        int e = t * 64 + b;
        if (e < PRE && ((sk[e] >> 32) > 0x007FFFFFull)) w |= 1ull << b;
      }
    }
    valid[n * 128 + t] = w;
  }
}

// ---------------------------------------------------------------------------
// K4b: IoU>=0.7 bitmask, UPPER TRIANGLE ONLY (jb >= ib).  (validated r4)
// ---------------------------------------------------------------------------
__global__ __launch_bounds__(64) void k_mask(const float4* __restrict__ sbox,
                                             u64* __restrict__ mask) {
  const int p = blockIdx.x;           /* 0..4464 */
  const int n = blockIdx.y;
  int ib = (int)((189.0 - sqrt(35721.0 - 8.0 * (double)p)) * 0.5);
  while (94 * (ib + 1) - (ib * (ib + 1)) / 2 <= p) ++ib;
  while (94 * ib - ((ib - 1) * ib) / 2 > p) --ib;
  const int jb = ib + (p - (94 * ib - ((ib - 1) * ib) / 2));

  const int r = threadIdx.x;
  const int i = ib * 64 + r;
  __shared__ float4 jbox[64];
  jbox[r] = sbox[(size_t)n * NCAP + jb * 64 + r];
  __syncthreads();
  const float4 pbx = sbox[(size_t)n * NCAP + i];
  const float pa = __fmul_rn(__fsub_rn(pbx.z, pbx.x), __fsub_rn(pbx.w, pbx.y));
  u64 word = 0;
#pragma unroll 8
  for (int b = 0; b < 64; ++b) {
    const float4 q = jbox[b];
    float ltx = fmaxf(pbx.x, q.x);
    float lty = fmaxf(pbx.y, q.y);
    float rbx = fminf(pbx.z, q.z);
    float rby = fminf(pbx.w, q.w);
    float wv = fmaxf(__fsub_rn(rbx, ltx), 0.0f);
    float hv = fmaxf(__fsub_rn(rby, lty), 0.0f);
    float inter = __fmul_rn(wv, hv);
    float a2 = __fmul_rn(__fsub_rn(q.z, q.x), __fsub_rn(q.w, q.y));
    float denom = __fadd_rn(__fsub_rn(__fadd_rn(pa, a2), inter), 1e-9f);
    float iou = __fdiv_rn(inter, denom);
    if (iou >= 0.7f) word |= (1ull << b);
  }
  mask[((size_t)(n * NCAP) + i) * NW + jb] = word;
}

// ---------------------------------------------------------------------------
// K4c (r9): streaming bit-scan, DEPTH-3 group prefetch (r8 depth-2 measured
// -9us; loads stay decision-independent per the r5/r7 lesson).  Decision
// logic bit-identical to r4.
// ---------------------------------------------------------------------------
__global__ __launch_bounds__(64) void k_scan(const u64* __restrict__ mask,
                                             const u64* __restrict__ valid,
                                             const float4* __restrict__ sbox,
                                             float* __restrict__ out) {
  const int n = blockIdx.x;
  const int lane = threadIdx.x;
  u64 s0 = 0, s1 = 0;
  const u64 v0 = valid[n * 128 + 2 * lane];
  const u64 v1 = valid[n * 128 + 2 * lane + 1];
  const u64* mrow = mask + (size_t)n * NCAP * NW;
  __shared__ int keep_list[POST];
  int kept = 0;

  const int NG = PRE / 16;   /* 375 */
  ulonglong2 c0[16], c1[16], c2[16], c3[16];
#pragma unroll
  for (int r = 0; r < 16; ++r)
    c0[r] = ((const ulonglong2*)(mrow + (size_t)r * NW))[lane];
#pragma unroll
  for (int r = 0; r < 16; ++r)
    c1[r] = ((const ulonglong2*)(mrow + (size_t)(16 + r) * NW))[lane];
#pragma unroll
  for (int r = 0; r < 16; ++r)
    c2[r] = ((const ulonglong2*)(mrow + (size_t)(32 + r) * NW))[lane];

  for (int g = 0; g < NG; ++g) {
    if (kept >= POST) break;
    if (g + 3 < NG) {
#pragma unroll
      for (int r = 0; r < 16; ++r)
        c3[r] = ((const ulonglong2*)(mrow + (size_t)((g + 3) * 16 + r) * NW))[lane];
    }
#pragma unroll
    for (int r = 0; r < 16; ++r) {
      if (kept < POST) {
        const int i = g * 16 + r;
        const int w = i >> 6;
        const u64 avail = (w & 1) ? (v1 & ~s1) : (v0 & ~s0);
        const unsigned h32 = (unsigned)(avail >> (i & 32));
        const unsigned wrd = __shfl(h32, w >> 1, 64);
        if ((wrd >> (i & 31)) & 1u) {
          if (lane == 0) keep_list[kept] = i;
          ++kept;
          s0 |= c0[r].x;
          s1 |= c0[r].y;
        }
      }
    }
#pragma unroll
    for (int r = 0; r < 16; ++r) { c0[r] = c1[r]; c1[r] = c2[r]; c2[r] = c3[r]; }
  }
  __syncthreads();

  for (int it = lane; it < POST; it += 64) {
    const int cand = (it < kept) ? keep_list[it] : 0;
    const float4 b = sbox[(size_t)n * NCAP + cand];
    float* orow = out + ((size_t)n * POST + it) * 4;
    orow[0] = b.x; orow[1] = b.y; orow[2] = b.z; orow[3] = b.w;
    out[(size_t)NIMG * POST * 4 + (size_t)n * POST + it] = (float)n;
  }
}

extern "C" void kernel_launch(void* const* d_in, const int* in_sizes, int n_in,
                              void* d_out, int out_size, void* d_ws, size_t ws_size,
                              hipStream_t stream) {
  const float* x    = (const float*)d_in[0];
  const float* w1   = (const float*)d_in[1];
  const float* b1   = (const float*)d_in[2];
  const float* wcls = (const float*)d_in[3];
  const float* bcls = (const float*)d_in[4];
  const float* wbb  = (const float*)d_in[5];
  const float* bbb  = (const float*)d_in[6];
  float* out = (float*)d_out;

  char* ws = (char*)d_ws;
  size_t off = 0;
  float* feat = (float*)(ws + off);               off += (size_t)NIMG * HW * CIN * 4;
  float* scores = (float*)(ws + off);             off += (size_t)NIMG * KPER * 4;
  float4* boxes = (float4*)(ws + off);            off += (size_t)NIMG * KPER * 16;
  float4* sbox = (float4*)(ws + off);             off += (size_t)NIMG * NCAP * 16;
  u64* valid = (u64*)(ws + off);                  off += (size_t)NIMG * 128 * 8;
  u64* mask = (u64*)(ws + off);                   off += (size_t)NIMG * NCAP * NW * 8;
  float* WHT2 = (float*)(ws + off);               off += (size_t)WHT_ELEMS * 4;
  float* bh   = (float*)(ws + off);               off += 256;
  unsigned short* xTh = (unsigned short*)(ws + off); off += XT_BYTES;
  unsigned short* xTl = (unsigned short*)(ws + off); off += XT_BYTES;
  unsigned short* wpk = (unsigned short*)(ws + off); off += WPK_ELEMS * 2;

  k_prep_all<<<PB_TOT, 256, 0, stream>>>((const float4*)x, w1, wcls, bcls, wbb, bbb,
                                         xTh, xTl, wpk, WHT2, bh);
  k_convmfma<<<800, 256, 0, stream>>>(xTh, xTl, wpk, b1, feat);
  k_head<<<(NIMG * HW) / 16, 256, 0, stream>>>(feat, WHT2, bh, scores, boxes);
  k_select<<<NIMG, SELT, 0, stream>>>(scores, boxes, sbox, valid);
  k_mask<<<dim3(NTRI, NIMG), 64, 0, stream>>>(sbox, mask);
  k_scan<<<NIMG, 64, 0, stream>>>(mask, valid, sbox, out);
}

// Round 10
// 789.124 us; speedup vs baseline: 1.1004x; 1.1004x over previous
//
#include <hip/hip_runtime.h>
#include <math.h>

#define NIMG 8
#define CIN  512
#define HF   50
#define WF   64
#define HW   3200
#define NA   9
#define KPER 28800   /* HW*NA per image */
#define PRE  6000
#define POST 300

#define WHT_ELEMS  32768     /* 512*64 */

/* sorted-candidate padding: 94 words * 64 = 6016 rows */
#define NW    94             /* u64 words per mask row */
#define NCAP  6016           /* padded candidate count */
#define NTRI  4465           /* NW*(NW+1)/2 upper-tri blocks */

/* padded NHWC f16 input: rows 52 (row p holds x row p-1; p=0,51 zero),
   cols 66 (col w' holds x col w'-1; w'=0,65 zero), ci contiguous. */
#define XTROWS 52
#define XTCOLS 66
#define XT_ELEMS ((size_t)NIMG * XTROWS * XTCOLS * CIN)   /* 14,057,472 */
#define XT_BYTES (XT_ELEMS * 2)                            /* 28,114,944 */

/* packed weights: [sp2][cob4][tap9][ks16][4096 f16] in LDS-physical tile order */
#define WPK_ELEMS ((size_t)2 * 4 * 9 * 16 * 4096)          /* 4,718,592 */
#define WPK_HALF  (4 * 9 * 16 * 4096)                      /* 2,359,296 */

/* scaling: x' = x*2^8, w' = w*2^14; acc scale 2^22 undone in epilogue */
#define SCALE_X 256.0f
#define SCALE_W 16384.0f
#define INV_SCALE (1.0f / 4194304.0f)   /* 2^-22 */

/* prep_all block ranges */
#define PB_XT   1600
#define PB_HALO 64
#define PB_WPK  288
#define PB_PH   16
#define PB_TOT  (PB_XT + PB_HALO + PB_WPK + PB_PH)   /* 1968 */

/* halo vec8 counts */
#define HALO_VPI 14848        /* vec8 per image per array */
#define HALO_TOT (NIMG * HALO_VPI)   /* 118,784 */

typedef _Float16 f16x8 __attribute__((ext_vector_type(8)));
typedef float f32x4  __attribute__((ext_vector_type(4)));
typedef unsigned short u16x8 __attribute__((ext_vector_type(8)));
typedef unsigned long long u64;

// Base anchors (x1,y1,x2,y2) computed in double, rounded to f32 (matches np.float32 cast)
__constant__ float BASEA[9][4] = {
  {-82.509667991878083f, -37.254833995939042f,  98.509667991878083f,  53.254833995939042f},
  {-173.01933598375617f, -82.509667991878083f, 189.01933598375617f,   98.509667991878083f},
  {-354.03867196751233f, -173.01933598375617f, 370.03867196751233f,  189.01933598375617f},
  { -56.0f,  -56.0f,  72.0f,  72.0f},
  {-120.0f, -120.0f, 136.0f, 136.0f},
  {-248.0f, -248.0f, 264.0f, 264.0f},
  {-37.254833995939042f, -82.509667991878083f,  53.254833995939042f,  98.509667991878083f},
  {-82.509667991878083f, -173.01933598375617f,  98.509667991878083f, 189.01933598375617f},
  {-173.01933598375617f, -354.03867196751233f, 189.01933598375617f,  370.03867196751233f},
};

__device__ __forceinline__ unsigned int ordf(float f) {
  unsigned int u = __float_as_uint(f);
  return (u & 0x80000000u) ? ~u : (u | 0x80000000u);
}

__device__ __forceinline__ unsigned short f2h(float f) {
  union { _Float16 h; unsigned short u; } cv;
  cv.h = (_Float16)f;             /* v_cvt_f16_f32, RNE */
  return cv.u;
}
__device__ __forceinline__ float h2f(unsigned short u) {
  union { _Float16 h; unsigned short u; } cv;
  cv.u = u;
  return (float)cv.h;
}

// ---------------------------------------------------------------------------
// P: fused prep (validated r4).
// ---------------------------------------------------------------------------
__global__ __launch_bounds__(256) void k_prep_all(
    const float4* __restrict__ x4,
    const float* __restrict__ w1,
    const float* __restrict__ wc, const float* __restrict__ bc,
    const float* __restrict__ wb, const float* __restrict__ bb,
    unsigned short* __restrict__ xh, unsigned short* __restrict__ xl,
    unsigned short* __restrict__ wpk,
    float* __restrict__ WHT2, float* __restrict__ bh) {
  __shared__ float tile[128][65];
  const int blk = blockIdx.x;
  const int t = threadIdx.x;

  if (blk < PB_XT) {
    const int cic = blk & 3;
    const int rest = blk >> 2;
    const int hrow = rest % 50;
    const int n = rest / 50;
#pragma unroll
    for (int jj = 0; jj < 8; ++jj) {
      const int e = t + 256 * jj;              /* 0..2047 */
      const int row = e >> 4, c4 = e & 15;
      const float4 v = x4[(((size_t)(n * CIN + cic * 128 + row) * HF + hrow) << 4) + c4];
      tile[row][c4 * 4 + 0] = v.x;
      tile[row][c4 * 4 + 1] = v.y;
      tile[row][c4 * 4 + 2] = v.z;
      tile[row][c4 * 4 + 3] = v.w;
    }
    __syncthreads();
#pragma unroll
    for (int jj = 0; jj < 4; ++jj) {
      const int e = t + 256 * jj;              /* 0..1023 */
      const int w = e >> 4, c8 = e & 15;
      const size_t base = ((size_t)((n * XTROWS + (hrow + 1)) * XTCOLS) + (w + 1)) * CIN
                          + cic * 128 + c8 * 8;
      u16x8 hv, lv;
#pragma unroll
      for (int u = 0; u < 8; ++u) {
        const float g = tile[c8 * 8 + u][w] * SCALE_X;
        const unsigned short hh = f2h(g);
        hv[u] = (short)hh;
        lv[u] = (short)f2h(g - h2f(hh));
      }
      *reinterpret_cast<u16x8*>(xh + base) = hv;
      *reinterpret_cast<u16x8*>(xl + base) = lv;
    }
  } else if (blk < PB_XT + PB_HALO) {
    const u16x8 z = {0, 0, 0, 0, 0, 0, 0, 0};
    const int tid = (blk - PB_XT) * 256 + t;   /* 0..16383 */
    for (int v = tid; v < HALO_TOT; v += PB_HALO * 256) {
      const int n = v / HALO_VPI;
      const int r = v - n * HALO_VPI;
      int row, col, v8;
      if (r < 8448) {                       /* rows 0,51 : 2*66*64 */
        row = (r < 4224) ? 0 : 51;
        const int r2 = (r < 4224) ? r : r - 4224;
        col = r2 >> 6;
        v8 = r2 & 63;
      } else {                              /* rows 1..50, cols 0/65 */
        const int q = r - 8448;             /* 0..6399 */
        row = 1 + (q >> 7);
        const int rr = q & 127;
        col = (rr >= 64) ? 65 : 0;
        v8 = rr & 63;
      }
      const size_t off = ((size_t)((n * XTROWS + row) * XTCOLS) + col) * CIN + v8 * 8;
      *reinterpret_cast<u16x8*>(xh + off) = z;
      *reinterpret_cast<u16x8*>(xl + off) = z;
    }
  } else if (blk < PB_XT + PB_HALO + PB_WPK) {
    const int tot = (int)WPK_ELEMS;
    const int tid = (blk - PB_XT - PB_HALO) * 256 + t;
    for (int idx = tid; idx < tot; idx += PB_WPK * 256) {
      const int i = idx & 4095;
      int rest = idx >> 12;
      const int ks = rest & 15; rest >>= 4;
      const int tap = rest % 9; rest /= 9;
      const int cob = rest & 3;
      const int sp = rest >> 2;
      const int col = i >> 5;
      const int slotp = (i >> 3) & 3;
      const int j = i & 7;
      const int s = slotp ^ ((col >> 1) & 3);
      const int ci = ks * 32 + s * 8 + j;
      const int co = cob * 128 + col;
      const float g = w1[((size_t)co * CIN + ci) * 9 + tap] * SCALE_W;
      const unsigned short hh = f2h(g);
      wpk[idx] = sp ? f2h(g - h2f(hh)) : hh;
    }
  } else {
    const int TOT = WHT_ELEMS + 64;
    const int tid = (blk - PB_XT - PB_HALO - PB_WPK) * 256 + t;
    for (int idx = tid; idx < TOT; idx += PB_PH * 256) {
      if (idx < WHT_ELEMS) {
        int r = idx & 3;
        int o = (idx >> 2) & 63;
        int c = (idx >> 8) * 4 + r;
        float v = 0.0f;
        if (o < 18) v = wc[(size_t)o * CIN + c];
        else if (o < 54) v = wb[(size_t)(o - 18) * CIN + c];
        WHT2[idx] = v;
      } else {
        int o = idx - WHT_ELEMS;
        float v = 0.0f;
        if (o < 18) v = bc[o];
        else if (o < 54) v = bb[o - 18];
        bh[o] = v;
      }
    }
  }
}

// ---------------------------------------------------------------------------
// K1 (r10): same 128x128 MFMA tile & numerics as r8, but SINGLE-buffered LDS
// (32 KiB) -> 5 blocks/CU: all 800 blocks co-resident (kills the 800-on-512
// grid-quantization tail) and cross-block wave overlap hides the now-exposed
// staging latency (guide m114 mechanism).  Accumulation order unchanged ->
// bit-identical feat.
// ---------------------------------------------------------------------------
#define GLDS(gp, lp) __builtin_amdgcn_global_load_lds( \
    (const __attribute__((address_space(1))) unsigned int*)(gp), \
    (__attribute__((address_space(3))) unsigned int*)(lp), 16, 0, 0)

__global__ __launch_bounds__(256) void k_convmfma(
    const unsigned short* __restrict__ xh,
    const unsigned short* __restrict__ xl,
    const unsigned short* __restrict__ wpk,
    const float* __restrict__ b1,
    float* __restrict__ feat) {
  __shared__ unsigned short lds[4][4096];   /* 32 KiB: [Ah,Al,Bh,Bl] */

  const int raw = blockIdx.x;
  const int xcd = raw & 7;
  const int idx = raw >> 3;          /* 0..99 */
  const int cob = xcd >> 1;          /* 0..3 */
  const int pb  = (xcd & 1) * 100 + idx;   /* 0..199 : n*25 + hb */

  const int n   = pb / 25;
  const int h0  = (pb - n * 25) * 2;
  const int t   = threadIdx.x;
  const int wid = t >> 6;
  const int l   = t & 63;
  const int wm  = wid >> 1;          /* wave M index (co) */
  const int wn  = wid & 1;           /* wave N index (pos row) */

  const int colp = l >> 2;                               /* w within 16-col group */
  const int sB = (((l & 3) ^ ((l >> 3) & 3)) << 3);      /* swizzled k-slot elem off */
  const unsigned short* xsrc = (wid == 3) ? xl : xh;
  const size_t wA_base = (size_t)(wid & 1) * WPK_HALF;

  const int fr = l & 15;
  const int fq = l >> 4;
  const int slotr = ((fq ^ ((fr >> 1) & 3)) << 4);       /* swizzled 16B slot (bytes) */

  f32x4 acc[4][4] = {};

  auto stage = [&](int ti) {
    const int ks  = ti / 9;          /* ci chunk  (slow) */
    const int tap = ti - ks * 9;     /* 3x3 tap   (fast: L2 reuse of x rows) */
    if (wid < 2) {
      const unsigned short* gp = wpk + wA_base
          + ((size_t)((cob * 9 + tap) * 16 + ks) << 12) + l * 8;
      unsigned short* lp = &lds[wid][0];
#pragma unroll
      for (int q = 0; q < 8; ++q)
        GLDS(gp + q * 512, lp + q * 512);
    } else {
      const int ky = (tap * 11) >> 5;       /* tap/3 for 0..8 */
      const int kx = tap - ky * 3;
      const size_t ebase = ((size_t)((n * XTROWS + h0 + ky) * XTCOLS + kx + colp) << 9)
                           + ks * 32 + sB;
      unsigned short* lp = &lds[wid][0];
#pragma unroll
      for (int q = 0; q < 8; ++q)
        GLDS(xsrc + ebase + ((size_t)(((q >> 2) * XTCOLS + (q & 3) * 16)) << 9),
             lp + q * 512);
    }
  };

  stage(0);

  for (int ti = 0; ti < 144; ++ti) {
    __syncthreads();       /* drains vmcnt(0): staged data for ti ready */

    f16x8 ah[4], al[4], bhf[4], blf[4];
#pragma unroll
    for (int mi = 0; mi < 4; ++mi) {
      const int off = (((wm << 6) + (mi << 4) + fr) << 6) + slotr;
      ah[mi] = *(const f16x8*)((const char*)&lds[0][0] + off);
      al[mi] = *(const f16x8*)((const char*)&lds[1][0] + off);
    }
#pragma unroll
    for (int ni = 0; ni < 4; ++ni) {
      const int off = (((wn << 6) + (ni << 4) + fr) << 6) + slotr;
      bhf[ni] = *(const f16x8*)((const char*)&lds[2][0] + off);
      blf[ni] = *(const f16x8*)((const char*)&lds[3][0] + off);
    }
#pragma unroll
    for (int mi = 0; mi < 4; ++mi)
#pragma unroll
      for (int ni = 0; ni < 4; ++ni) {
        acc[mi][ni] = __builtin_amdgcn_mfma_f32_16x16x32_f16(ah[mi], bhf[ni], acc[mi][ni], 0, 0, 0);
        acc[mi][ni] = __builtin_amdgcn_mfma_f32_16x16x32_f16(ah[mi], blf[ni], acc[mi][ni], 0, 0, 0);
        acc[mi][ni] = __builtin_amdgcn_mfma_f32_16x16x32_f16(al[mi], bhf[ni], acc[mi][ni], 0, 0, 0);
      }
    __syncthreads();       /* all waves done reading lds for ti */
    if (ti < 143) stage(ti + 1);   /* safe to overwrite */
  }

  const int h = h0 + wn;
#pragma unroll
  for (int mi = 0; mi < 4; ++mi) {
    const int co = (cob << 7) + (wm << 6) + (mi << 4) + (fq << 2);
    const float4 bias = *(const float4*)&b1[co];
#pragma unroll
    for (int ni = 0; ni < 4; ++ni) {
      const int w = (ni << 4) + fr;
      float4 v;
      v.x = fmaxf(fmaf(acc[mi][ni][0], INV_SCALE, bias.x), 0.0f);
      v.y = fmaxf(fmaf(acc[mi][ni][1], INV_SCALE, bias.y), 0.0f);
      v.z = fmaxf(fmaf(acc[mi][ni][2], INV_SCALE, bias.z), 0.0f);
      v.w = fmaxf(fmaf(acc[mi][ni][3], INV_SCALE, bias.w), 0.0f);
      *(float4*)(feat + (((size_t)n * HW + h * WF + w) << 9) + co) = v;
    }
  }
}

// ---------------------------------------------------------------------------
// K2: 1x1 heads + softmax-fg + box decode + clip + min-size filter.
// (identical numerics to validated r2 kernel; r7: float4 feat staging)
// ---------------------------------------------------------------------------
__global__ __launch_bounds__(256) void k_head(const float* __restrict__ feat,
                                              const float* __restrict__ WHT2,
                                              const float* __restrict__ bh,
                                              float* __restrict__ scores,
                                              float4* __restrict__ boxes) {
  __shared__ float fsh[16][512];
  __shared__ float vsh[16][64];
  const int t = threadIdx.x;
  const int wvid = t >> 6;
  const int o = t & 63;
  const int pos0 = blockIdx.x * 16;

  {
    const float4* fsrc = reinterpret_cast<const float4*>(feat + ((size_t)pos0 << 9));
    float4* fdst = reinterpret_cast<float4*>(&fsh[0][0]);
#pragma unroll
    for (int i = 0; i < 8; ++i) fdst[t + 256 * i] = fsrc[t + 256 * i];
  }
  __syncthreads();

  {
    const int p0 = wvid * 4;
    float a0 = 0.f, a1 = 0.f, a2 = 0.f, a3 = 0.f;
    const float4* wp = reinterpret_cast<const float4*>(WHT2);
    const float4* f0 = reinterpret_cast<const float4*>(&fsh[p0 + 0][0]);
    const float4* f1 = reinterpret_cast<const float4*>(&fsh[p0 + 1][0]);
    const float4* f2 = reinterpret_cast<const float4*>(&fsh[p0 + 2][0]);
    const float4* f3 = reinterpret_cast<const float4*>(&fsh[p0 + 3][0]);
#pragma unroll 4
    for (int c4 = 0; c4 < 128; ++c4) {
      float4 w4 = wp[c4 * 64 + o];
      float4 v;
      v = f0[c4];
      a0 = fmaf(w4.x, v.x, a0); a0 = fmaf(w4.y, v.y, a0);
      a0 = fmaf(w4.z, v.z, a0); a0 = fmaf(w4.w, v.w, a0);
      v = f1[c4];
      a1 = fmaf(w4.x, v.x, a1); a1 = fmaf(w4.y, v.y, a1);
      a1 = fmaf(w4.z, v.z, a1); a1 = fmaf(w4.w, v.w, a1);
      v = f2[c4];
      a2 = fmaf(w4.x, v.x, a2); a2 = fmaf(w4.y, v.y, a2);
      a2 = fmaf(w4.z, v.z, a2); a2 = fmaf(w4.w, v.w, a2);
      v = f3[c4];
      a3 = fmaf(w4.x, v.x, a3); a3 = fmaf(w4.y, v.y, a3);
      a3 = fmaf(w4.z, v.z, a3); a3 = fmaf(w4.w, v.w, a3);
    }
    float bv = bh[o];
    vsh[p0 + 0][o] = a0 + bv;
    vsh[p0 + 1][o] = a1 + bv;
    vsh[p0 + 2][o] = a2 + bv;
    vsh[p0 + 3][o] = a3 + bv;
  }
  __syncthreads();

  if (t < 144) {
    const int p2 = t / 9, a = t % 9;
    const int pos = pos0 + p2;
    const int n = pos / HW;
    const int r = pos - n * HW;
    const int ph = r >> 6;
    const int pw = r & 63;

    float l0 = vsh[p2][a * 2];
    float l1 = vsh[p2][a * 2 + 1];
    float m  = fmaxf(l0, l1);
    float e0 = (float)exp((double)__fsub_rn(l0, m));
    float e1 = (float)exp((double)__fsub_rn(l1, m));
    float fg = __fdiv_rn(e1, __fadd_rn(e0, e1));

    float d0 = vsh[p2][18 + a * 4 + 0];
    float d1 = vsh[p2][18 + a * 4 + 1];
    float d2 = vsh[p2][18 + a * 4 + 2];
    float d3 = vsh[p2][18 + a * 4 + 3];

    float sx = (float)(pw * 16);
    float sy = (float)(ph * 16);
    float ax1 = __fadd_rn(BASEA[a][0], sx);
    float ay1 = __fadd_rn(BASEA[a][1], sy);
    float ax2 = __fadd_rn(BASEA[a][2], sx);
    float ay2 = __fadd_rn(BASEA[a][3], sy);
    float aw = __fsub_rn(ax2, ax1);
    float ah = __fsub_rn(ay2, ay1);
    float acx = __fadd_rn(ax1, __fmul_rn(0.5f, aw));
    float acy = __fadd_rn(ay1, __fmul_rn(0.5f, ah));
    float cx = __fadd_rn(__fmul_rn(d0, aw), acx);
    float cy = __fadd_rn(__fmul_rn(d1, ah), acy);
    float pwd = __fmul_rn((float)exp((double)d2), aw);
    float phd = __fmul_rn((float)exp((double)d3), ah);
    float x1 = __fsub_rn(cx, __fmul_rn(0.5f, pwd));
    float y1 = __fsub_rn(cy, __fmul_rn(0.5f, phd));
    float x2 = __fadd_rn(cx, __fmul_rn(0.5f, pwd));
    float y2 = __fadd_rn(cy, __fmul_rn(0.5f, phd));
    x1 = fminf(fmaxf(x1, 0.0f), 1024.0f);
    x2 = fminf(fmaxf(x2, 0.0f), 1024.0f);
    y1 = fminf(fmaxf(y1, 0.0f), 800.0f);
    y2 = fminf(fmaxf(y2, 0.0f), 800.0f);
    float wsz = __fsub_rn(x2, x1);
    float hsz = __fsub_rn(y2, y1);
    float sc = (wsz >= 16.0f && hsz >= 16.0f) ? fg : -__builtin_huge_valf();

    const int idx = n * KPER + r * NA + a;
    scores[idx] = sc;
    boxes[idx] = make_float4(x1, y1, x2, y2);
  }
}

// ---------------------------------------------------------------------------
// K3 (merged topk + sort, validated r4/r6; r7 float4 score loads; back to
// 1024 threads -- the r9 256-thread variant lost TLP on the KPER-wide passes).
// ---------------------------------------------------------------------------
__global__ __launch_bounds__(1024) void k_select(const float* __restrict__ scores,
                                                 const float4* __restrict__ boxes,
                                                 float4* __restrict__ sbox,
                                                 u64* __restrict__ valid) {
  __shared__ u64 sk[8192];
  __shared__ unsigned int whist[16][264];   /* per-wave, 264-stride staggers banks */
  __shared__ unsigned int histT[256];
  __shared__ unsigned int sh_selB, sh_ngt, sh_binc, sh_num;
  const int n = blockIdx.x;
  const int t = threadIdx.x;
  const int wv = t >> 6;
  const float* sc = scores + (size_t)n * KPER;
  const float4* sc4 = reinterpret_cast<const float4*>(sc);

  for (int e = t; e < 8192; e += 1024) sk[e] = 0ull;   /* pad + slots */

  unsigned int prefix = 0, prefMask = 0, ngt = 0, neq = 0;
  for (int shift = 24; shift >= 0; shift -= 8) {
    for (int e = t; e < 16 * 264; e += 1024) (&whist[0][0])[e] = 0u;
    __syncthreads();
    for (int i4 = t; i4 < KPER / 4; i4 += 1024) {
      const float4 v = sc4[i4];
      unsigned int u;
      u = ordf(v.x); if ((u & prefMask) == prefix) atomicAdd(&whist[wv][(u >> shift) & 255], 1u);
      u = ordf(v.y); if ((u & prefMask) == prefix) atomicAdd(&whist[wv][(u >> shift) & 255], 1u);
      u = ordf(v.z); if ((u & prefMask) == prefix) atomicAdd(&whist[wv][(u >> shift) & 255], 1u);
      u = ordf(v.w); if ((u & prefMask) == prefix) atomicAdd(&whist[wv][(u >> shift) & 255], 1u);
    }
    __syncthreads();
    if (t < 256) {
      unsigned int s = 0;
#pragma unroll
      for (int w = 0; w < 16; ++w) s += whist[w][t];
      histT[t] = s;
    }
    __syncthreads();
    if (t == 0) {
      unsigned int cnt = ngt;
      for (int b = 255; b >= 0; --b) {
        unsigned int c = histT[b];
        if (cnt + c >= (unsigned)PRE) { sh_selB = (unsigned)b; sh_ngt = cnt; sh_binc = c; break; }
        cnt += c;
      }
    }
    __syncthreads();
    prefix |= (sh_selB << shift);
    prefMask |= (0xFFu << shift);
    ngt = sh_ngt;
    neq = sh_binc;
    __syncthreads();
  }
  const unsigned int T = prefix;
  const unsigned int needed = (unsigned)PRE - ngt;
  unsigned int J = 0xFFFFFFFFu;
  if (needed < neq) {
    if (t < 256) histT[t] = 0;
    __syncthreads();
    for (int i = t; i < KPER; i += 1024)
      if (ordf(sc[i]) == T) atomicAdd(&histT[i >> 7], 1u);
    __syncthreads();
    if (t == 0) {
      unsigned int cnt = 0;
      for (int b = 0; b < 256; ++b) {
        unsigned int c = histT[b];
        if (cnt + c >= needed) { sh_selB = (unsigned)b; sh_ngt = needed - cnt; break; }
        cnt += c;
      }
    }
    __syncthreads();
    const unsigned int selH = sh_selB;
    const unsigned int needLow = sh_ngt;
    __syncthreads();
    if (t < 128) histT[t] = 0;
    __syncthreads();
    for (int i = t; i < KPER; i += 1024)
      if (ordf(sc[i]) == T && ((unsigned)(i >> 7)) == selH) atomicAdd(&histT[i & 127], 1u);
    __syncthreads();
    if (t == 0) {
      unsigned int cnt = 0;
      for (int b = 0; b < 128; ++b) {
        unsigned int c = histT[b];
        if (cnt + c >= needLow) { sh_selB = (selH << 7) | (unsigned)b; break; }
        cnt += c;
      }
    }
    __syncthreads();
    J = sh_selB;
  }

  if (t == 0) sh_num = 0;
  __syncthreads();
  for (int i4 = t; i4 < KPER / 4; i4 += 1024) {
    const float4 v = sc4[i4];
    const float vv[4] = {v.x, v.y, v.z, v.w};
#pragma unroll
    for (int c = 0; c < 4; ++c) {
      const int i = i4 * 4 + c;
      unsigned int u = ordf(vv[c]);
      bool in = (u > T) || (u == T && (unsigned)i <= J);
      if (in) {
        unsigned int p = atomicAdd(&sh_num, 1u);
        sk[p] = (((u64)u) << 32) | (u64)(~(unsigned int)i);
      }
    }
  }
  __syncthreads();

  /* bitonic sort descending, 8192 elems (pad 0 sorts to tail) */
  for (int k = 2; k <= 8192; k <<= 1) {
    for (int j = k >> 1; j > 0; j >>= 1) {
      for (int p = t; p < 4096; p += 1024) {
        const int i = ((p & ~(j - 1)) << 1) | (p & (j - 1));
        const int ip = i | j;
        u64 a = sk[i], b = sk[ip];
        const bool desc = ((i & k) == 0);
        if ((a < b) == desc) { sk[i] = b; sk[ip] = a; }
      }
      __syncthreads();
    }
  }

  /* gather sorted boxes + valid bitmap */
  for (int e = t; e < NCAP; e += 1024) {
    float4 bx = make_float4(0.f, 0.f, 0.f, 0.f);
    if (e < PRE) {
      unsigned idx = ~(unsigned)(sk[e] & 0xFFFFFFFFull);
      bx = boxes[(size_t)n * KPER + idx];
    }
    sbox[(size_t)n * NCAP + e] = bx;
  }
  if (t < 128) {
    u64 w = 0;
    if (t < NW) {
      for (int b = 0; b < 64; ++b) {
        int e = t * 64 + b;
        if (e < PRE && ((sk[e] >> 32) > 0x007FFFFFull)) w |= 1ull << b;
      }
    }
    valid[n * 128 + t] = w;
  }
}

// ---------------------------------------------------------------------------
// K4b: IoU>=0.7 bitmask, UPPER TRIANGLE ONLY (jb >= ib).  (validated r4)
// ---------------------------------------------------------------------------
__global__ __launch_bounds__(64) void k_mask(const float4* __restrict__ sbox,
                                             u64* __restrict__ mask) {
  const int p = blockIdx.x;           /* 0..4464 */
  const int n = blockIdx.y;
  int ib = (int)((189.0 - sqrt(35721.0 - 8.0 * (double)p)) * 0.5);
  while (94 * (ib + 1) - (ib * (ib + 1)) / 2 <= p) ++ib;
  while (94 * ib - ((ib - 1) * ib) / 2 > p) --ib;
  const int jb = ib + (p - (94 * ib - ((ib - 1) * ib) / 2));

  const int r = threadIdx.x;
  const int i = ib * 64 + r;
  __shared__ float4 jbox[64];
  jbox[r] = sbox[(size_t)n * NCAP + jb * 64 + r];
  __syncthreads();
  const float4 pbx = sbox[(size_t)n * NCAP + i];
  const float pa = __fmul_rn(__fsub_rn(pbx.z, pbx.x), __fsub_rn(pbx.w, pbx.y));
  u64 word = 0;
#pragma unroll 8
  for (int b = 0; b < 64; ++b) {
    const float4 q = jbox[b];
    float ltx = fmaxf(pbx.x, q.x);
    float lty = fmaxf(pbx.y, q.y);
    float rbx = fminf(pbx.z, q.z);
    float rby = fminf(pbx.w, q.w);
    float wv = fmaxf(__fsub_rn(rbx, ltx), 0.0f);
    float hv = fmaxf(__fsub_rn(rby, lty), 0.0f);
    float inter = __fmul_rn(wv, hv);
    float a2 = __fmul_rn(__fsub_rn(q.z, q.x), __fsub_rn(q.w, q.y));
    float denom = __fadd_rn(__fsub_rn(__fadd_rn(pa, a2), inter), 1e-9f);
    float iou = __fdiv_rn(inter, denom);
    if (iou >= 0.7f) word |= (1ull << b);
  }
  mask[((size_t)(n * NCAP) + i) * NW + jb] = word;
}

// ---------------------------------------------------------------------------
// K4c (r8, validated): streaming bit-scan with DEPTH-2 group prefetch.
// Loads independent of decisions; decision logic bit-identical to r4.
// ---------------------------------------------------------------------------
__global__ __launch_bounds__(64) void k_scan(const u64* __restrict__ mask,
                                             const u64* __restrict__ valid,
                                             const float4* __restrict__ sbox,
                                             float* __restrict__ out) {
  const int n = blockIdx.x;
  const int lane = threadIdx.x;
  u64 s0 = 0, s1 = 0;
  const u64 v0 = valid[n * 128 + 2 * lane];
  const u64 v1 = valid[n * 128 + 2 * lane + 1];
  const u64* mrow = mask + (size_t)n * NCAP * NW;
  __shared__ int keep_list[POST];
  int kept = 0;

  const int NG = PRE / 16;   /* 375 */
  ulonglong2 c0[16], c1[16], c2[16];
#pragma unroll
  for (int r = 0; r < 16; ++r)
    c0[r] = ((const ulonglong2*)(mrow + (size_t)r * NW))[lane];
#pragma unroll
  for (int r = 0; r < 16; ++r)
    c1[r] = ((const ulonglong2*)(mrow + (size_t)(16 + r) * NW))[lane];

  for (int g = 0; g < NG; ++g) {
    if (kept >= POST) break;
    if (g + 2 < NG) {
#pragma unroll
      for (int r = 0; r < 16; ++r)
        c2[r] = ((const ulonglong2*)(mrow + (size_t)((g + 2) * 16 + r) * NW))[lane];
    }
#pragma unroll
    for (int r = 0; r < 16; ++r) {
      if (kept < POST) {
        const int i = g * 16 + r;
        const int w = i >> 6;
        const u64 avail = (w & 1) ? (v1 & ~s1) : (v0 & ~s0);
        const unsigned h32 = (unsigned)(avail >> (i & 32));
        const unsigned wrd = __shfl(h32, w >> 1, 64);
        if ((wrd >> (i & 31)) & 1u) {
          if (lane == 0) keep_list[kept] = i;
          ++kept;
          s0 |= c0[r].x;
          s1 |= c0[r].y;
        }
      }
    }
#pragma unroll
    for (int r = 0; r < 16; ++r) { c0[r] = c1[r]; c1[r] = c2[r]; }
  }
  __syncthreads();

  for (int it = lane; it < POST; it += 64) {
    const int cand = (it < kept) ? keep_list[it] : 0;
    const float4 b = sbox[(size_t)n * NCAP + cand];
    float* orow = out + ((size_t)n * POST + it) * 4;
    orow[0] = b.x; orow[1] = b.y; orow[2] = b.z; orow[3] = b.w;
    out[(size_t)NIMG * POST * 4 + (size_t)n * POST + it] = (float)n;
  }
}

extern "C" void kernel_launch(void* const* d_in, const int* in_sizes, int n_in,
                              void* d_out, int out_size, void* d_ws, size_t ws_size,
                              hipStream_t stream) {
  const float* x    = (const float*)d_in[0];
  const float* w1   = (const float*)d_in[1];
  const float* b1   = (const float*)d_in[2];
  const float* wcls = (const float*)d_in[3];
  const float* bcls = (const float*)d_in[4];
  const float* wbb  = (const float*)d_in[5];
  const float* bbb  = (const float*)d_in[6];
  float* out = (float*)d_out;

  char* ws = (char*)d_ws;
  size_t off = 0;
  float* feat = (float*)(ws + off);               off += (size_t)NIMG * HW * CIN * 4;
  float* scores = (float*)(ws + off);             off += (size_t)NIMG * KPER * 4;
  float4* boxes = (float4*)(ws + off);            off += (size_t)NIMG * KPER * 16;
  float4* sbox = (float4*)(ws + off);             off += (size_t)NIMG * NCAP * 16;
  u64* valid = (u64*)(ws + off);                  off += (size_t)NIMG * 128 * 8;
  u64* mask = (u64*)(ws + off);                   off += (size_t)NIMG * NCAP * NW * 8;
  float* WHT2 = (float*)(ws + off);               off += (size_t)WHT_ELEMS * 4;
  float* bh   = (float*)(ws + off);               off += 256;
  unsigned short* xTh = (unsigned short*)(ws + off); off += XT_BYTES;
  unsigned short* xTl = (unsigned short*)(ws + off); off += XT_BYTES;
  unsigned short* wpk = (unsigned short*)(ws + off); off += WPK_ELEMS * 2;

  k_prep_all<<<PB_TOT, 256, 0, stream>>>((const float4*)x, w1, wcls, bcls, wbb, bbb,
                                         xTh, xTl, wpk, WHT2, bh);
  k_convmfma<<<800, 256, 0, stream>>>(xTh, xTl, wpk, b1, feat);
  k_head<<<(NIMG * HW) / 16, 256, 0, stream>>>(feat, WHT2, bh, scores, boxes);
  k_select<<<NIMG, 1024, 0, stream>>>(scores, boxes, sbox, valid);
  k_mask<<<dim3(NTRI, NIMG), 64, 0, stream>>>(sbox, mask);
  k_scan<<<NIMG, 64, 0, stream>>>(mask, valid, sbox, out);
}

// Round 11
// 724.664 us; speedup vs baseline: 1.1982x; 1.0890x over previous
//
#include <hip/hip_runtime.h>
#include <math.h>

#define NIMG 8
#define CIN  512
#define HF   50
#define WF   64
#define HW   3200
#define NA   9
#define KPER 28800   /* HW*NA per image */
#define PRE  6000
#define POST 300

#define WHT_ELEMS  32768     /* 512*64 */

/* sorted-candidate padding: 94 words * 64 = 6016 rows */
#define NW    94             /* u64 words per mask row */
#define NCAP  6016           /* padded candidate count */
#define NTRI  4465           /* NW*(NW+1)/2 upper-tri blocks */

/* padded NHWC f16 input: rows 52 (row p holds x row p-1; p=0,51 zero),
   cols 66 (col w' holds x col w'-1; w'=0,65 zero), ci contiguous. */
#define XTROWS 52
#define XTCOLS 66
#define XT_ELEMS ((size_t)NIMG * XTROWS * XTCOLS * CIN)   /* 14,057,472 */
#define XT_BYTES (XT_ELEMS * 2)                            /* 28,114,944 */

/* packed weights: [sp2][cob4][tap9][ks16][4096 f16] in LDS-physical tile order */
#define WPK_ELEMS ((size_t)2 * 4 * 9 * 16 * 4096)          /* 4,718,592 */
#define WPK_HALF  (4 * 9 * 16 * 4096)                      /* 2,359,296 */

/* scaling: x' = x*2^8, w' = w*2^14; acc scale 2^22 undone in epilogue */
#define SCALE_X 256.0f
#define SCALE_W 16384.0f
#define INV_SCALE (1.0f / 4194304.0f)   /* 2^-22 */

/* prep_all block ranges */
#define PB_XT   1600
#define PB_HALO 64
#define PB_WPK  288
#define PB_PH   16
#define PB_TOT  (PB_XT + PB_HALO + PB_WPK + PB_PH)   /* 1968 */

/* halo vec8 counts */
#define HALO_VPI 14848        /* vec8 per image per array */
#define HALO_TOT (NIMG * HALO_VPI)   /* 118,784 */

typedef _Float16 f16x8 __attribute__((ext_vector_type(8)));
typedef float f32x4  __attribute__((ext_vector_type(4)));
typedef unsigned short u16x8 __attribute__((ext_vector_type(8)));
typedef unsigned long long u64;

// Base anchors (x1,y1,x2,y2) computed in double, rounded to f32 (matches np.float32 cast)
__constant__ float BASEA[9][4] = {
  {-82.509667991878083f, -37.254833995939042f,  98.509667991878083f,  53.254833995939042f},
  {-173.01933598375617f, -82.509667991878083f, 189.01933598375617f,   98.509667991878083f},
  {-354.03867196751233f, -173.01933598375617f, 370.03867196751233f,  189.01933598375617f},
  { -56.0f,  -56.0f,  72.0f,  72.0f},
  {-120.0f, -120.0f, 136.0f, 136.0f},
  {-248.0f, -248.0f, 264.0f, 264.0f},
  {-37.254833995939042f, -82.509667991878083f,  53.254833995939042f,  98.509667991878083f},
  {-82.509667991878083f, -173.01933598375617f,  98.509667991878083f, 189.01933598375617f},
  {-173.01933598375617f, -354.03867196751233f, 189.01933598375617f,  370.03867196751233f},
};

__device__ __forceinline__ unsigned int ordf(float f) {
  unsigned int u = __float_as_uint(f);
  return (u & 0x80000000u) ? ~u : (u | 0x80000000u);
}

__device__ __forceinline__ unsigned short f2h(float f) {
  union { _Float16 h; unsigned short u; } cv;
  cv.h = (_Float16)f;             /* v_cvt_f16_f32, RNE */
  return cv.u;
}
__device__ __forceinline__ float h2f(unsigned short u) {
  union { _Float16 h; unsigned short u; } cv;
  cv.u = u;
  return (float)cv.h;
}

// ---------------------------------------------------------------------------
// P: fused prep (validated r4).
// ---------------------------------------------------------------------------
__global__ __launch_bounds__(256) void k_prep_all(
    const float4* __restrict__ x4,
    const float* __restrict__ w1,
    const float* __restrict__ wc, const float* __restrict__ bc,
    const float* __restrict__ wb, const float* __restrict__ bb,
    unsigned short* __restrict__ xh, unsigned short* __restrict__ xl,
    unsigned short* __restrict__ wpk,
    float* __restrict__ WHT2, float* __restrict__ bh) {
  __shared__ float tile[128][65];
  const int blk = blockIdx.x;
  const int t = threadIdx.x;

  if (blk < PB_XT) {
    const int cic = blk & 3;
    const int rest = blk >> 2;
    const int hrow = rest % 50;
    const int n = rest / 50;
#pragma unroll
    for (int jj = 0; jj < 8; ++jj) {
      const int e = t + 256 * jj;              /* 0..2047 */
      const int row = e >> 4, c4 = e & 15;
      const float4 v = x4[(((size_t)(n * CIN + cic * 128 + row) * HF + hrow) << 4) + c4];
      tile[row][c4 * 4 + 0] = v.x;
      tile[row][c4 * 4 + 1] = v.y;
      tile[row][c4 * 4 + 2] = v.z;
      tile[row][c4 * 4 + 3] = v.w;
    }
    __syncthreads();
#pragma unroll
    for (int jj = 0; jj < 4; ++jj) {
      const int e = t + 256 * jj;              /* 0..1023 */
      const int w = e >> 4, c8 = e & 15;
      const size_t base = ((size_t)((n * XTROWS + (hrow + 1)) * XTCOLS) + (w + 1)) * CIN
                          + cic * 128 + c8 * 8;
      u16x8 hv, lv;
#pragma unroll
      for (int u = 0; u < 8; ++u) {
        const float g = tile[c8 * 8 + u][w] * SCALE_X;
        const unsigned short hh = f2h(g);
        hv[u] = (short)hh;
        lv[u] = (short)f2h(g - h2f(hh));
      }
      *reinterpret_cast<u16x8*>(xh + base) = hv;
      *reinterpret_cast<u16x8*>(xl + base) = lv;
    }
  } else if (blk < PB_XT + PB_HALO) {
    const u16x8 z = {0, 0, 0, 0, 0, 0, 0, 0};
    const int tid = (blk - PB_XT) * 256 + t;   /* 0..16383 */
    for (int v = tid; v < HALO_TOT; v += PB_HALO * 256) {
      const int n = v / HALO_VPI;
      const int r = v - n * HALO_VPI;
      int row, col, v8;
      if (r < 8448) {                       /* rows 0,51 : 2*66*64 */
        row = (r < 4224) ? 0 : 51;
        const int r2 = (r < 4224) ? r : r - 4224;
        col = r2 >> 6;
        v8 = r2 & 63;
      } else {                              /* rows 1..50, cols 0/65 */
        const int q = r - 8448;             /* 0..6399 */
        row = 1 + (q >> 7);
        const int rr = q & 127;
        col = (rr >= 64) ? 65 : 0;
        v8 = rr & 63;
      }
      const size_t off = ((size_t)((n * XTROWS + row) * XTCOLS) + col) * CIN + v8 * 8;
      *reinterpret_cast<u16x8*>(xh + off) = z;
      *reinterpret_cast<u16x8*>(xl + off) = z;
    }
  } else if (blk < PB_XT + PB_HALO + PB_WPK) {
    const int tot = (int)WPK_ELEMS;
    const int tid = (blk - PB_XT - PB_HALO) * 256 + t;
    for (int idx = tid; idx < tot; idx += PB_WPK * 256) {
      const int i = idx & 4095;
      int rest = idx >> 12;
      const int ks = rest & 15; rest >>= 4;
      const int tap = rest % 9; rest /= 9;
      const int cob = rest & 3;
      const int sp = rest >> 2;
      const int col = i >> 5;
      const int slotp = (i >> 3) & 3;
      const int j = i & 7;
      const int s = slotp ^ ((col >> 1) & 3);
      const int ci = ks * 32 + s * 8 + j;
      const int co = cob * 128 + col;
      const float g = w1[((size_t)co * CIN + ci) * 9 + tap] * SCALE_W;
      const unsigned short hh = f2h(g);
      wpk[idx] = sp ? f2h(g - h2f(hh)) : hh;
    }
  } else {
    const int TOT = WHT_ELEMS + 64;
    const int tid = (blk - PB_XT - PB_HALO - PB_WPK) * 256 + t;
    for (int idx = tid; idx < TOT; idx += PB_PH * 256) {
      if (idx < WHT_ELEMS) {
        int r = idx & 3;
        int o = (idx >> 2) & 63;
        int c = (idx >> 8) * 4 + r;
        float v = 0.0f;
        if (o < 18) v = wc[(size_t)o * CIN + c];
        else if (o < 54) v = wb[(size_t)(o - 18) * CIN + c];
        WHT2[idx] = v;
      } else {
        int o = idx - WHT_ELEMS;
        float v = 0.0f;
        if (o < 18) v = bc[o];
        else if (o < 54) v = bb[o - 18];
        bh[o] = v;
      }
    }
  }
}

// ---------------------------------------------------------------------------
// K1 (r11): dual-pos-tile MFMA conv.  Block = 512 thr (8 waves, 2M x 4N),
// output 128co x 256pos (two pb tiles: pp and pp+100 -- same rows, images
// n and n+4).  A (weights) staged ONCE per step for both pos tiles:
// 48KB/step serving 384 MFMA (128 B/MFMA vs r8's 170); barriers per output
// FLOP halved.  Double-buffered LDS 96KB (proven schedule).  Per-thread frag
// reads / MFMA count / accumulation order identical to r8 -> bit-identical
// feat.  Grid 400; XCD swizzle keeps one cob (2.36MB) per XCD L2-resident.
// ---------------------------------------------------------------------------
#define GLDS(gp, lp) __builtin_amdgcn_global_load_lds( \
    (const __attribute__((address_space(1))) unsigned int*)(gp), \
    (__attribute__((address_space(3))) unsigned int*)(lp), 16, 0, 0)

__global__ __launch_bounds__(512, 2) void k_convmfma(
    const unsigned short* __restrict__ xh,
    const unsigned short* __restrict__ xl,
    const unsigned short* __restrict__ wpk,
    const float* __restrict__ b1,
    float* __restrict__ feat) {
  __shared__ unsigned short lds[2][6][4096];   /* 96 KiB: [buf][Ah,Al,B0h,B0l,B1h,B1l] */

  const int raw = blockIdx.x;        /* 0..399 */
  const int xcd = raw & 7;
  const int idx = raw >> 3;          /* 0..49 */
  const int cob = xcd >> 1;          /* 0..3 */
  const int pp  = (xcd & 1) * 50 + idx;    /* 0..99 */
  const int pb0 = pp;                /* images 0..3 */
  const int pb1 = pp + 100;          /* images 4..7, same rows */

  const int n0 = pb0 / 25, h00 = (pb0 - n0 * 25) * 2;
  const int n1 = pb1 / 25, h10 = (pb1 - n1 * 25) * 2;

  const int t   = threadIdx.x;
  const int wid = t >> 6;            /* 0..7 */
  const int l   = t & 63;
  const int wm  = wid >> 2;          /* 0..1 : 64-co half */
  const int wn  = wid & 3;           /* 0..3 : 64-pos quarter (0,1->pb0; 2,3->pb1) */

  /* staging constants */
  const int colp = l >> 2;                               /* w within 16-col group */
  const int sB = (((l & 3) ^ ((l >> 3) & 3)) << 3);      /* swizzled k-slot elem off */

  /* fragment-read constants */
  const int fr = l & 15;
  const int fq = l >> 4;
  const int slotr = ((fq ^ ((fr >> 1) & 3)) << 4);       /* swizzled 16B slot (bytes) */

  /* per-wave B staging geometry (waves 2..5) */
  const int bsel = (wid - 2) >> 1;         /* 0 -> pb0, 1 -> pb1 */
  const unsigned short* xsrc = ((wid - 2) & 1) ? xl : xh;
  const int bn  = bsel ? n1 : n0;
  const int bh0 = bsel ? h10 : h00;

  f32x4 acc[4][4] = {};

  auto stage = [&](int sbuf, int ti) {
    const int ks  = ti / 9;          /* ci chunk  (slow) */
    const int tap = ti - ks * 9;     /* 3x3 tap   (fast: L2 reuse of x rows) */
    if (wid < 2) {
      /* A tiles: wid0 -> hi, wid1 -> lo (shared by both pos tiles) */
      const unsigned short* gp = wpk + (size_t)wid * WPK_HALF
          + ((size_t)((cob * 9 + tap) * 16 + ks) << 12) + l * 8;
      unsigned short* lp = &lds[sbuf][wid][0];
#pragma unroll
      for (int q = 0; q < 8; ++q)
        GLDS(gp + q * 512, lp + q * 512);
    } else if (wid < 6) {
      /* B tiles: wid2 B0h, wid3 B0l, wid4 B1h, wid5 B1l */
      const int ky = (tap * 11) >> 5;       /* tap/3 for 0..8 */
      const int kx = tap - ky * 3;
      const size_t ebase = ((size_t)((bn * XTROWS + bh0 + ky) * XTCOLS + kx + colp) << 9)
                           + ks * 32 + sB;
      unsigned short* lp = &lds[sbuf][wid][0];
#pragma unroll
      for (int q = 0; q < 8; ++q)
        GLDS(xsrc + ebase + ((size_t)(((q >> 2) * XTCOLS + (q & 3) * 16)) << 9),
             lp + q * 512);
    }
  };

  stage(0, 0);
  __syncthreads();

  const int btile = 2 + ((wn >> 1) << 1);  /* 2 (B0h) or 4 (B1h); +1 is lo */

  int buf = 0;
  for (int ti = 0; ti < 144; ++ti) {
    if (ti < 143) stage(buf ^ 1, ti + 1);   /* issue next-step loads first */

    f16x8 ah[4], al[4], bhf[4], blf[4];
#pragma unroll
    for (int mi = 0; mi < 4; ++mi) {
      const int off = (((wm << 6) + (mi << 4) + fr) << 6) + slotr;
      ah[mi] = *(const f16x8*)((const char*)&lds[buf][0][0] + off);
      al[mi] = *(const f16x8*)((const char*)&lds[buf][1][0] + off);
    }
#pragma unroll
    for (int ni = 0; ni < 4; ++ni) {
      const int off = ((((wn & 1) << 6) + (ni << 4) + fr) << 6) + slotr;
      bhf[ni] = *(const f16x8*)((const char*)&lds[buf][btile][0] + off);
      blf[ni] = *(const f16x8*)((const char*)&lds[buf][btile + 1][0] + off);
    }
#pragma unroll
    for (int mi = 0; mi < 4; ++mi)
#pragma unroll
      for (int ni = 0; ni < 4; ++ni) {
        acc[mi][ni] = __builtin_amdgcn_mfma_f32_16x16x32_f16(ah[mi], bhf[ni], acc[mi][ni], 0, 0, 0);
        acc[mi][ni] = __builtin_amdgcn_mfma_f32_16x16x32_f16(ah[mi], blf[ni], acc[mi][ni], 0, 0, 0);
        acc[mi][ni] = __builtin_amdgcn_mfma_f32_16x16x32_f16(al[mi], bhf[ni], acc[mi][ni], 0, 0, 0);
      }
    __syncthreads();                        /* drains vmcnt(0): next buf ready */
    buf ^= 1;
  }

  /* epilogue: rescale 2^-22 + bias + relu, float4 per lane into NHWC feat */
  const int pbE = (wn < 2) ? pb0 : pb1;
  const int nE  = (wn < 2) ? n0 : n1;
  const int h   = ((wn < 2) ? h00 : h10) + (wn & 1);
  (void)pbE;
#pragma unroll
  for (int mi = 0; mi < 4; ++mi) {
    const int co = (cob << 7) + (wm << 6) + (mi << 4) + (fq << 2);
    const float4 bias = *(const float4*)&b1[co];
#pragma unroll
    for (int ni = 0; ni < 4; ++ni) {
      const int w = (ni << 4) + fr;
      float4 v;
      v.x = fmaxf(fmaf(acc[mi][ni][0], INV_SCALE, bias.x), 0.0f);
      v.y = fmaxf(fmaf(acc[mi][ni][1], INV_SCALE, bias.y), 0.0f);
      v.z = fmaxf(fmaf(acc[mi][ni][2], INV_SCALE, bias.z), 0.0f);
      v.w = fmaxf(fmaf(acc[mi][ni][3], INV_SCALE, bias.w), 0.0f);
      *(float4*)(feat + (((size_t)nE * HW + h * WF + w) << 9) + co) = v;
    }
  }
}

// ---------------------------------------------------------------------------
// K2: 1x1 heads + softmax-fg + box decode + clip + min-size filter.
// (identical numerics to validated r2 kernel; r7: float4 feat staging)
// ---------------------------------------------------------------------------
__global__ __launch_bounds__(256) void k_head(const float* __restrict__ feat,
                                              const float* __restrict__ WHT2,
                                              const float* __restrict__ bh,
                                              float* __restrict__ scores,
                                              float4* __restrict__ boxes) {
  __shared__ float fsh[16][512];
  __shared__ float vsh[16][64];
  const int t = threadIdx.x;
  const int wvid = t >> 6;
  const int o = t & 63;
  const int pos0 = blockIdx.x * 16;

  {
    const float4* fsrc = reinterpret_cast<const float4*>(feat + ((size_t)pos0 << 9));
    float4* fdst = reinterpret_cast<float4*>(&fsh[0][0]);
#pragma unroll
    for (int i = 0; i < 8; ++i) fdst[t + 256 * i] = fsrc[t + 256 * i];
  }
  __syncthreads();

  {
    const int p0 = wvid * 4;
    float a0 = 0.f, a1 = 0.f, a2 = 0.f, a3 = 0.f;
    const float4* wp = reinterpret_cast<const float4*>(WHT2);
    const float4* f0 = reinterpret_cast<const float4*>(&fsh[p0 + 0][0]);
    const float4* f1 = reinterpret_cast<const float4*>(&fsh[p0 + 1][0]);
    const float4* f2 = reinterpret_cast<const float4*>(&fsh[p0 + 2][0]);
    const float4* f3 = reinterpret_cast<const float4*>(&fsh[p0 + 3][0]);
#pragma unroll 4
    for (int c4 = 0; c4 < 128; ++c4) {
      float4 w4 = wp[c4 * 64 + o];
      float4 v;
      v = f0[c4];
      a0 = fmaf(w4.x, v.x, a0); a0 = fmaf(w4.y, v.y, a0);
      a0 = fmaf(w4.z, v.z, a0); a0 = fmaf(w4.w, v.w, a0);
      v = f1[c4];
      a1 = fmaf(w4.x, v.x, a1); a1 = fmaf(w4.y, v.y, a1);
      a1 = fmaf(w4.z, v.z, a1); a1 = fmaf(w4.w, v.w, a1);
      v = f2[c4];
      a2 = fmaf(w4.x, v.x, a2); a2 = fmaf(w4.y, v.y, a2);
      a2 = fmaf(w4.z, v.z, a2); a2 = fmaf(w4.w, v.w, a2);
      v = f3[c4];
      a3 = fmaf(w4.x, v.x, a3); a3 = fmaf(w4.y, v.y, a3);
      a3 = fmaf(w4.z, v.z, a3); a3 = fmaf(w4.w, v.w, a3);
    }
    float bv = bh[o];
    vsh[p0 + 0][o] = a0 + bv;
    vsh[p0 + 1][o] = a1 + bv;
    vsh[p0 + 2][o] = a2 + bv;
    vsh[p0 + 3][o] = a3 + bv;
  }
  __syncthreads();

  if (t < 144) {
    const int p2 = t / 9, a = t % 9;
    const int pos = pos0 + p2;
    const int n = pos / HW;
    const int r = pos - n * HW;
    const int ph = r >> 6;
    const int pw = r & 63;

    float l0 = vsh[p2][a * 2];
    float l1 = vsh[p2][a * 2 + 1];
    float m  = fmaxf(l0, l1);
    float e0 = (float)exp((double)__fsub_rn(l0, m));
    float e1 = (float)exp((double)__fsub_rn(l1, m));
    float fg = __fdiv_rn(e1, __fadd_rn(e0, e1));

    float d0 = vsh[p2][18 + a * 4 + 0];
    float d1 = vsh[p2][18 + a * 4 + 1];
    float d2 = vsh[p2][18 + a * 4 + 2];
    float d3 = vsh[p2][18 + a * 4 + 3];

    float sx = (float)(pw * 16);
    float sy = (float)(ph * 16);
    float ax1 = __fadd_rn(BASEA[a][0], sx);
    float ay1 = __fadd_rn(BASEA[a][1], sy);
    float ax2 = __fadd_rn(BASEA[a][2], sx);
    float ay2 = __fadd_rn(BASEA[a][3], sy);
    float aw = __fsub_rn(ax2, ax1);
    float ah = __fsub_rn(ay2, ay1);
    float acx = __fadd_rn(ax1, __fmul_rn(0.5f, aw));
    float acy = __fadd_rn(ay1, __fmul_rn(0.5f, ah));
    float cx = __fadd_rn(__fmul_rn(d0, aw), acx);
    float cy = __fadd_rn(__fmul_rn(d1, ah), acy);
    float pwd = __fmul_rn((float)exp((double)d2), aw);
    float phd = __fmul_rn((float)exp((double)d3), ah);
    float x1 = __fsub_rn(cx, __fmul_rn(0.5f, pwd));
    float y1 = __fsub_rn(cy, __fmul_rn(0.5f, phd));
    float x2 = __fadd_rn(cx, __fmul_rn(0.5f, pwd));
    float y2 = __fadd_rn(cy, __fmul_rn(0.5f, phd));
    x1 = fminf(fmaxf(x1, 0.0f), 1024.0f);
    x2 = fminf(fmaxf(x2, 0.0f), 1024.0f);
    y1 = fminf(fmaxf(y1, 0.0f), 800.0f);
    y2 = fminf(fmaxf(y2, 0.0f), 800.0f);
    float wsz = __fsub_rn(x2, x1);
    float hsz = __fsub_rn(y2, y1);
    float sc = (wsz >= 16.0f && hsz >= 16.0f) ? fg : -__builtin_huge_valf();

    const int idx = n * KPER + r * NA + a;
    scores[idx] = sc;
    boxes[idx] = make_float4(x1, y1, x2, y2);
  }
}

// ---------------------------------------------------------------------------
// K3 (merged topk + sort, validated r4/r6; r7 float4 score loads; 1024 thr).
// ---------------------------------------------------------------------------
__global__ __launch_bounds__(1024) void k_select(const float* __restrict__ scores,
                                                 const float4* __restrict__ boxes,
                                                 float4* __restrict__ sbox,
                                                 u64* __restrict__ valid) {
  __shared__ u64 sk[8192];
  __shared__ unsigned int whist[16][264];   /* per-wave, 264-stride staggers banks */
  __shared__ unsigned int histT[256];
  __shared__ unsigned int sh_selB, sh_ngt, sh_binc, sh_num;
  const int n = blockIdx.x;
  const int t = threadIdx.x;
  const int wv = t >> 6;
  const float* sc = scores + (size_t)n * KPER;
  const float4* sc4 = reinterpret_cast<const float4*>(sc);

  for (int e = t; e < 8192; e += 1024) sk[e] = 0ull;   /* pad + slots */

  unsigned int prefix = 0, prefMask = 0, ngt = 0, neq = 0;
  for (int shift = 24; shift >= 0; shift -= 8) {
    for (int e = t; e < 16 * 264; e += 1024) (&whist[0][0])[e] = 0u;
    __syncthreads();
    for (int i4 = t; i4 < KPER / 4; i4 += 1024) {
      const float4 v = sc4[i4];
      unsigned int u;
      u = ordf(v.x); if ((u & prefMask) == prefix) atomicAdd(&whist[wv][(u >> shift) & 255], 1u);
      u = ordf(v.y); if ((u & prefMask) == prefix) atomicAdd(&whist[wv][(u >> shift) & 255], 1u);
      u = ordf(v.z); if ((u & prefMask) == prefix) atomicAdd(&whist[wv][(u >> shift) & 255], 1u);
      u = ordf(v.w); if ((u & prefMask) == prefix) atomicAdd(&whist[wv][(u >> shift) & 255], 1u);
    }
    __syncthreads();
    if (t < 256) {
      unsigned int s = 0;
#pragma unroll
      for (int w = 0; w < 16; ++w) s += whist[w][t];
      histT[t] = s;
    }
    __syncthreads();
    if (t == 0) {
      unsigned int cnt = ngt;
      for (int b = 255; b >= 0; --b) {
        unsigned int c = histT[b];
        if (cnt + c >= (unsigned)PRE) { sh_selB = (unsigned)b; sh_ngt = cnt; sh_binc = c; break; }
        cnt += c;
      }
    }
    __syncthreads();
    prefix |= (sh_selB << shift);
    prefMask |= (0xFFu << shift);
    ngt = sh_ngt;
    neq = sh_binc;
    __syncthreads();
  }
  const unsigned int T = prefix;
  const unsigned int needed = (unsigned)PRE - ngt;
  unsigned int J = 0xFFFFFFFFu;
  if (needed < neq) {
    if (t < 256) histT[t] = 0;
    __syncthreads();
    for (int i = t; i < KPER; i += 1024)
      if (ordf(sc[i]) == T) atomicAdd(&histT[i >> 7], 1u);
    __syncthreads();
    if (t == 0) {
      unsigned int cnt = 0;
      for (int b = 0; b < 256; ++b) {
        unsigned int c = histT[b];
        if (cnt + c >= needed) { sh_selB = (unsigned)b; sh_ngt = needed - cnt; break; }
        cnt += c;
      }
    }
    __syncthreads();
    const unsigned int selH = sh_selB;
    const unsigned int needLow = sh_ngt;
    __syncthreads();
    if (t < 128) histT[t] = 0;
    __syncthreads();
    for (int i = t; i < KPER; i += 1024)
      if (ordf(sc[i]) == T && ((unsigned)(i >> 7)) == selH) atomicAdd(&histT[i & 127], 1u);
    __syncthreads();
    if (t == 0) {
      unsigned int cnt = 0;
      for (int b = 0; b < 128; ++b) {
        unsigned int c = histT[b];
        if (cnt + c >= needLow) { sh_selB = (selH << 7) | (unsigned)b; break; }
        cnt += c;
      }
    }
    __syncthreads();
    J = sh_selB;
  }

  if (t == 0) sh_num = 0;
  __syncthreads();
  for (int i4 = t; i4 < KPER / 4; i4 += 1024) {
    const float4 v = sc4[i4];
    const float vv[4] = {v.x, v.y, v.z, v.w};
#pragma unroll
    for (int c = 0; c < 4; ++c) {
      const int i = i4 * 4 + c;
      unsigned int u = ordf(vv[c]);
      bool in = (u > T) || (u == T && (unsigned)i <= J);
      if (in) {
        unsigned int p = atomicAdd(&sh_num, 1u);
        sk[p] = (((u64)u) << 32) | (u64)(~(unsigned int)i);
      }
    }
  }
  __syncthreads();

  /* bitonic sort descending, 8192 elems (pad 0 sorts to tail) */
  for (int k = 2; k <= 8192; k <<= 1) {
    for (int j = k >> 1; j > 0; j >>= 1) {
      for (int p = t; p < 4096; p += 1024) {
        const int i = ((p & ~(j - 1)) << 1) | (p & (j - 1));
        const int ip = i | j;
        u64 a = sk[i], b = sk[ip];
        const bool desc = ((i & k) == 0);
        if ((a < b) == desc) { sk[i] = b; sk[ip] = a; }
      }
      __syncthreads();
    }
  }

  /* gather sorted boxes + valid bitmap */
  for (int e = t; e < NCAP; e += 1024) {
    float4 bx = make_float4(0.f, 0.f, 0.f, 0.f);
    if (e < PRE) {
      unsigned idx = ~(unsigned)(sk[e] & 0xFFFFFFFFull);
      bx = boxes[(size_t)n * KPER + idx];
    }
    sbox[(size_t)n * NCAP + e] = bx;
  }
  if (t < 128) {
    u64 w = 0;
    if (t < NW) {
      for (int b = 0; b < 64; ++b) {
        int e = t * 64 + b;
        if (e < PRE && ((sk[e] >> 32) > 0x007FFFFFull)) w |= 1ull << b;
      }
    }
    valid[n * 128 + t] = w;
  }
}

// ---------------------------------------------------------------------------
// K4b: IoU>=0.7 bitmask, UPPER TRIANGLE ONLY (jb >= ib).  (validated r4)
// ---------------------------------------------------------------------------
__global__ __launch_bounds__(64) void k_mask(const float4* __restrict__ sbox,
                                             u64* __restrict__ mask) {
  const int p = blockIdx.x;           /* 0..4464 */
  const int n = blockIdx.y;
  int ib = (int)((189.0 - sqrt(35721.0 - 8.0 * (double)p)) * 0.5);
  while (94 * (ib + 1) - (ib * (ib + 1)) / 2 <= p) ++ib;
  while (94 * ib - ((ib - 1) * ib) / 2 > p) --ib;
  const int jb = ib + (p - (94 * ib - ((ib - 1) * ib) / 2));

  const int r = threadIdx.x;
  const int i = ib * 64 + r;
  __shared__ float4 jbox[64];
  jbox[r] = sbox[(size_t)n * NCAP + jb * 64 + r];
  __syncthreads();
  const float4 pbx = sbox[(size_t)n * NCAP + i];
  const float pa = __fmul_rn(__fsub_rn(pbx.z, pbx.x), __fsub_rn(pbx.w, pbx.y));
  u64 word = 0;
#pragma unroll 8
  for (int b = 0; b < 64; ++b) {
    const float4 q = jbox[b];
    float ltx = fmaxf(pbx.x, q.x);
    float lty = fmaxf(pbx.y, q.y);
    float rbx = fminf(pbx.z, q.z);
    float rby = fminf(pbx.w, q.w);
    float wv = fmaxf(__fsub_rn(rbx, ltx), 0.0f);
    float hv = fmaxf(__fsub_rn(rby, lty), 0.0f);
    float inter = __fmul_rn(wv, hv);
    float a2 = __fmul_rn(__fsub_rn(q.z, q.x), __fsub_rn(q.w, q.y));
    float denom = __fadd_rn(__fsub_rn(__fadd_rn(pa, a2), inter), 1e-9f);
    float iou = __fdiv_rn(inter, denom);
    if (iou >= 0.7f) word |= (1ull << b);
  }
  mask[((size_t)(n * NCAP) + i) * NW + jb] = word;
}

// ---------------------------------------------------------------------------
// K4c (r8, validated): streaming bit-scan with DEPTH-2 group prefetch.
// Loads independent of decisions; decision logic bit-identical to r4.
// ---------------------------------------------------------------------------
__global__ __launch_bounds__(64) void k_scan(const u64* __restrict__ mask,
                                             const u64* __restrict__ valid,
                                             const float4* __restrict__ sbox,
                                             float* __restrict__ out) {
  const int n = blockIdx.x;
  const int lane = threadIdx.x;
  u64 s0 = 0, s1 = 0;
  const u64 v0 = valid[n * 128 + 2 * lane];
  const u64 v1 = valid[n * 128 + 2 * lane + 1];
  const u64* mrow = mask + (size_t)n * NCAP * NW;
  __shared__ int keep_list[POST];
  int kept = 0;

  const int NG = PRE / 16;   /* 375 */
  ulonglong2 c0[16], c1[16], c2[16];
#pragma unroll
  for (int r = 0; r < 16; ++r)
    c0[r] = ((const ulonglong2*)(mrow + (size_t)r * NW))[lane];
#pragma unroll
  for (int r = 0; r < 16; ++r)
    c1[r] = ((const ulonglong2*)(mrow + (size_t)(16 + r) * NW))[lane];

  for (int g = 0; g < NG; ++g) {
    if (kept >= POST) break;
    if (g + 2 < NG) {
#pragma unroll
      for (int r = 0; r < 16; ++r)
        c2[r] = ((const ulonglong2*)(mrow + (size_t)((g + 2) * 16 + r) * NW))[lane];
    }
#pragma unroll
    for (int r = 0; r < 16; ++r) {
      if (kept < POST) {
        const int i = g * 16 + r;
        const int w = i >> 6;
        const u64 avail = (w & 1) ? (v1 & ~s1) : (v0 & ~s0);
        const unsigned h32 = (unsigned)(avail >> (i & 32));
        const unsigned wrd = __shfl(h32, w >> 1, 64);
        if ((wrd >> (i & 31)) & 1u) {
          if (lane == 0) keep_list[kept] = i;
          ++kept;
          s0 |= c0[r].x;
          s1 |= c0[r].y;
        }
      }
    }
#pragma unroll
    for (int r = 0; r < 16; ++r) { c0[r] = c1[r]; c1[r] = c2[r]; }
  }
  __syncthreads();

  for (int it = lane; it < POST; it += 64) {
    const int cand = (it < kept) ? keep_list[it] : 0;
    const float4 b = sbox[(size_t)n * NCAP + cand];
    float* orow = out + ((size_t)n * POST + it) * 4;
    orow[0] = b.x; orow[1] = b.y; orow[2] = b.z; orow[3] = b.w;
    out[(size_t)NIMG * POST * 4 + (size_t)n * POST + it] = (float)n;
  }
}

extern "C" void kernel_launch(void* const* d_in, const int* in_sizes, int n_in,
                              void* d_out, int out_size, void* d_ws, size_t ws_size,
                              hipStream_t stream) {
  const float* x    = (const float*)d_in[0];
  const float* w1   = (const float*)d_in[1];
  const float* b1   = (const float*)d_in[2];
  const float* wcls = (const float*)d_in[3];
  const float* bcls = (const float*)d_in[4];
  const float* wbb  = (const float*)d_in[5];
  const float* bbb  = (const float*)d_in[6];
  float* out = (float*)d_out;

  char* ws = (char*)d_ws;
  size_t off = 0;
  float* feat = (float*)(ws + off);               off += (size_t)NIMG * HW * CIN * 4;
  float* scores = (float*)(ws + off);             off += (size_t)NIMG * KPER * 4;
  float4* boxes = (float4*)(ws + off);            off += (size_t)NIMG * KPER * 16;
  float4* sbox = (float4*)(ws + off);             off += (size_t)NIMG * NCAP * 16;
  u64* valid = (u64*)(ws + off);                  off += (size_t)NIMG * 128 * 8;
  u64* mask = (u64*)(ws + off);                   off += (size_t)NIMG * NCAP * NW * 8;
  float* WHT2 = (float*)(ws + off);               off += (size_t)WHT_ELEMS * 4;
  float* bh   = (float*)(ws + off);               off += 256;
  unsigned short* xTh = (unsigned short*)(ws + off); off += XT_BYTES;
  unsigned short* xTl = (unsigned short*)(ws + off); off += XT_BYTES;
  unsigned short* wpk = (unsigned short*)(ws + off); off += WPK_ELEMS * 2;

  k_prep_all<<<PB_TOT, 256, 0, stream>>>((const float4*)x, w1, wcls, bcls, wbb, bbb,
                                         xTh, xTl, wpk, WHT2, bh);
  k_convmfma<<<400, 512, 0, stream>>>(xTh, xTl, wpk, b1, feat);
  k_head<<<(NIMG * HW) / 16, 256, 0, stream>>>(feat, WHT2, bh, scores, boxes);
  k_select<<<NIMG, 1024, 0, stream>>>(scores, boxes, sbox, valid);
  k_mask<<<dim3(NTRI, NIMG), 64, 0, stream>>>(sbox, mask);
  k_scan<<<NIMG, 64, 0, stream>>>(mask, valid, sbox, out);
}

// Round 12
// 721.681 us; speedup vs baseline: 1.2032x; 1.0041x over previous
//
#include <hip/hip_runtime.h>
#include <math.h>

#define NIMG 8
#define CIN  512
#define HF   50
#define WF   64
#define HW   3200
#define NA   9
#define KPER 28800   /* HW*NA per image */
#define PRE  6000
#define POST 300

#define WHT_ELEMS  32768     /* 512*64 */

/* sorted-candidate padding: 94 words * 64 = 6016 rows */
#define NW    94             /* u64 words per mask row */
#define NCAP  6016           /* padded candidate count */
#define NTRI  4465           /* NW*(NW+1)/2 upper-tri blocks */

/* padded NHWC f16 input: rows 52 (row p holds x row p-1; p=0,51 zero),
   cols 66 (col w' holds x col w'-1; w'=0,65 zero), ci contiguous. */
#define XTROWS 52
#define XTCOLS 66
#define XT_ELEMS ((size_t)NIMG * XTROWS * XTCOLS * CIN)   /* 14,057,472 */
#define XT_BYTES (XT_ELEMS * 2)                            /* 28,114,944 */

/* packed weights: [sp2][cob4][tap9][ks16][4096 f16] in LDS-physical tile order */
#define WPK_ELEMS ((size_t)2 * 4 * 9 * 16 * 4096)          /* 4,718,592 */
#define WPK_HALF  (4 * 9 * 16 * 4096)                      /* 2,359,296 */

/* scaling: x' = x*2^8, w' = w*2^14; acc scale 2^22 undone in epilogue */
#define SCALE_X 256.0f
#define SCALE_W 16384.0f
#define INV_SCALE (1.0f / 4194304.0f)   /* 2^-22 */

/* prep_all block ranges */
#define PB_XT   1600
#define PB_HALO 64
#define PB_WPK  288
#define PB_PH   16
#define PB_TOT  (PB_XT + PB_HALO + PB_WPK + PB_PH)   /* 1968 */

/* halo vec8 counts */
#define HALO_VPI 14848        /* vec8 per image per array */
#define HALO_TOT (NIMG * HALO_VPI)   /* 118,784 */

typedef _Float16 f16x8 __attribute__((ext_vector_type(8)));
typedef float f32x4  __attribute__((ext_vector_type(4)));
typedef unsigned short u16x8 __attribute__((ext_vector_type(8)));
typedef unsigned long long u64;

// Base anchors (x1,y1,x2,y2) computed in double, rounded to f32 (matches np.float32 cast)
__constant__ float BASEA[9][4] = {
  {-82.509667991878083f, -37.254833995939042f,  98.509667991878083f,  53.254833995939042f},
  {-173.01933598375617f, -82.509667991878083f, 189.01933598375617f,   98.509667991878083f},
  {-354.03867196751233f, -173.01933598375617f, 370.03867196751233f,  189.01933598375617f},
  { -56.0f,  -56.0f,  72.0f,  72.0f},
  {-120.0f, -120.0f, 136.0f, 136.0f},
  {-248.0f, -248.0f, 264.0f, 264.0f},
  {-37.254833995939042f, -82.509667991878083f,  53.254833995939042f,  98.509667991878083f},
  {-82.509667991878083f, -173.01933598375617f,  98.509667991878083f, 189.01933598375617f},
  {-173.01933598375617f, -354.03867196751233f, 189.01933598375617f,  370.03867196751233f},
};

__device__ __forceinline__ unsigned int ordf(float f) {
  unsigned int u = __float_as_uint(f);
  return (u & 0x80000000u) ? ~u : (u | 0x80000000u);
}

__device__ __forceinline__ unsigned short f2h(float f) {
  union { _Float16 h; unsigned short u; } cv;
  cv.h = (_Float16)f;             /* v_cvt_f16_f32, RNE */
  return cv.u;
}
__device__ __forceinline__ float h2f(unsigned short u) {
  union { _Float16 h; unsigned short u; } cv;
  cv.u = u;
  return (float)cv.h;
}

// ---------------------------------------------------------------------------
// P: fused prep (validated r4).
// ---------------------------------------------------------------------------
__global__ __launch_bounds__(256) void k_prep_all(
    const float4* __restrict__ x4,
    const float* __restrict__ w1,
    const float* __restrict__ wc, const float* __restrict__ bc,
    const float* __restrict__ wb, const float* __restrict__ bb,
    unsigned short* __restrict__ xh, unsigned short* __restrict__ xl,
    unsigned short* __restrict__ wpk,
    float* __restrict__ WHT2, float* __restrict__ bh) {
  __shared__ float tile[128][65];
  const int blk = blockIdx.x;
  const int t = threadIdx.x;

  if (blk < PB_XT) {
    const int cic = blk & 3;
    const int rest = blk >> 2;
    const int hrow = rest % 50;
    const int n = rest / 50;
#pragma unroll
    for (int jj = 0; jj < 8; ++jj) {
      const int e = t + 256 * jj;              /* 0..2047 */
      const int row = e >> 4, c4 = e & 15;
      const float4 v = x4[(((size_t)(n * CIN + cic * 128 + row) * HF + hrow) << 4) + c4];
      tile[row][c4 * 4 + 0] = v.x;
      tile[row][c4 * 4 + 1] = v.y;
      tile[row][c4 * 4 + 2] = v.z;
      tile[row][c4 * 4 + 3] = v.w;
    }
    __syncthreads();
#pragma unroll
    for (int jj = 0; jj < 4; ++jj) {
      const int e = t + 256 * jj;              /* 0..1023 */
      const int w = e >> 4, c8 = e & 15;
      const size_t base = ((size_t)((n * XTROWS + (hrow + 1)) * XTCOLS) + (w + 1)) * CIN
                          + cic * 128 + c8 * 8;
      u16x8 hv, lv;
#pragma unroll
      for (int u = 0; u < 8; ++u) {
        const float g = tile[c8 * 8 + u][w] * SCALE_X;
        const unsigned short hh = f2h(g);
        hv[u] = (short)hh;
        lv[u] = (short)f2h(g - h2f(hh));
      }
      *reinterpret_cast<u16x8*>(xh + base) = hv;
      *reinterpret_cast<u16x8*>(xl + base) = lv;
    }
  } else if (blk < PB_XT + PB_HALO) {
    const u16x8 z = {0, 0, 0, 0, 0, 0, 0, 0};
    const int tid = (blk - PB_XT) * 256 + t;   /* 0..16383 */
    for (int v = tid; v < HALO_TOT; v += PB_HALO * 256) {
      const int n = v / HALO_VPI;
      const int r = v - n * HALO_VPI;
      int row, col, v8;
      if (r < 8448) {                       /* rows 0,51 : 2*66*64 */
        row = (r < 4224) ? 0 : 51;
        const int r2 = (r < 4224) ? r : r - 4224;
        col = r2 >> 6;
        v8 = r2 & 63;
      } else {                              /* rows 1..50, cols 0/65 */
        const int q = r - 8448;             /* 0..6399 */
        row = 1 + (q >> 7);
        const int rr = q & 127;
        col = (rr >= 64) ? 65 : 0;
        v8 = rr & 63;
      }
      const size_t off = ((size_t)((n * XTROWS + row) * XTCOLS) + col) * CIN + v8 * 8;
      *reinterpret_cast<u16x8*>(xh + off) = z;
      *reinterpret_cast<u16x8*>(xl + off) = z;
    }
  } else if (blk < PB_XT + PB_HALO + PB_WPK) {
    const int tot = (int)WPK_ELEMS;
    const int tid = (blk - PB_XT - PB_HALO) * 256 + t;
    for (int idx = tid; idx < tot; idx += PB_WPK * 256) {
      const int i = idx & 4095;
      int rest = idx >> 12;
      const int ks = rest & 15; rest >>= 4;
      const int tap = rest % 9; rest /= 9;
      const int cob = rest & 3;
      const int sp = rest >> 2;
      const int col = i >> 5;
      const int slotp = (i >> 3) & 3;
      const int j = i & 7;
      const int s = slotp ^ ((col >> 1) & 3);
      const int ci = ks * 32 + s * 8 + j;
      const int co = cob * 128 + col;
      const float g = w1[((size_t)co * CIN + ci) * 9 + tap] * SCALE_W;
      const unsigned short hh = f2h(g);
      wpk[idx] = sp ? f2h(g - h2f(hh)) : hh;
    }
  } else {
    const int TOT = WHT_ELEMS + 64;
    const int tid = (blk - PB_XT - PB_HALO - PB_WPK) * 256 + t;
    for (int idx = tid; idx < TOT; idx += PB_PH * 256) {
      if (idx < WHT_ELEMS) {
        int r = idx & 3;
        int o = (idx >> 2) & 63;
        int c = (idx >> 8) * 4 + r;
        float v = 0.0f;
        if (o < 18) v = wc[(size_t)o * CIN + c];
        else if (o < 54) v = wb[(size_t)(o - 18) * CIN + c];
        WHT2[idx] = v;
      } else {
        int o = idx - WHT_ELEMS;
        float v = 0.0f;
        if (o < 18) v = bc[o];
        else if (o < 54) v = bb[o - 18];
        bh[o] = v;
      }
    }
  }
}

// ---------------------------------------------------------------------------
// K1 (r11, validated): dual-pos-tile MFMA conv.  512 thr, 128co x 256pos,
// A staged once per step; 96KB double-buffered LDS; XCD swizzle.
// ---------------------------------------------------------------------------
#define GLDS(gp, lp) __builtin_amdgcn_global_load_lds( \
    (const __attribute__((address_space(1))) unsigned int*)(gp), \
    (__attribute__((address_space(3))) unsigned int*)(lp), 16, 0, 0)

__global__ __launch_bounds__(512, 2) void k_convmfma(
    const unsigned short* __restrict__ xh,
    const unsigned short* __restrict__ xl,
    const unsigned short* __restrict__ wpk,
    const float* __restrict__ b1,
    float* __restrict__ feat) {
  __shared__ unsigned short lds[2][6][4096];   /* 96 KiB: [buf][Ah,Al,B0h,B0l,B1h,B1l] */

  const int raw = blockIdx.x;        /* 0..399 */
  const int xcd = raw & 7;
  const int idx = raw >> 3;          /* 0..49 */
  const int cob = xcd >> 1;          /* 0..3 */
  const int pp  = (xcd & 1) * 50 + idx;    /* 0..99 */
  const int pb0 = pp;                /* images 0..3 */
  const int pb1 = pp + 100;          /* images 4..7, same rows */

  const int n0 = pb0 / 25, h00 = (pb0 - n0 * 25) * 2;
  const int n1 = pb1 / 25, h10 = (pb1 - n1 * 25) * 2;

  const int t   = threadIdx.x;
  const int wid = t >> 6;            /* 0..7 */
  const int l   = t & 63;
  const int wm  = wid >> 2;          /* 0..1 : 64-co half */
  const int wn  = wid & 3;           /* 0..3 : 64-pos quarter (0,1->pb0; 2,3->pb1) */

  const int colp = l >> 2;                               /* w within 16-col group */
  const int sB = (((l & 3) ^ ((l >> 3) & 3)) << 3);      /* swizzled k-slot elem off */

  const int fr = l & 15;
  const int fq = l >> 4;
  const int slotr = ((fq ^ ((fr >> 1) & 3)) << 4);       /* swizzled 16B slot (bytes) */

  const int bsel = (wid - 2) >> 1;         /* 0 -> pb0, 1 -> pb1 */
  const unsigned short* xsrc = ((wid - 2) & 1) ? xl : xh;
  const int bn  = bsel ? n1 : n0;
  const int bh0 = bsel ? h10 : h00;

  f32x4 acc[4][4] = {};

  auto stage = [&](int sbuf, int ti) {
    const int ks  = ti / 9;          /* ci chunk  (slow) */
    const int tap = ti - ks * 9;     /* 3x3 tap   (fast: L2 reuse of x rows) */
    if (wid < 2) {
      const unsigned short* gp = wpk + (size_t)wid * WPK_HALF
          + ((size_t)((cob * 9 + tap) * 16 + ks) << 12) + l * 8;
      unsigned short* lp = &lds[sbuf][wid][0];
#pragma unroll
      for (int q = 0; q < 8; ++q)
        GLDS(gp + q * 512, lp + q * 512);
    } else if (wid < 6) {
      const int ky = (tap * 11) >> 5;       /* tap/3 for 0..8 */
      const int kx = tap - ky * 3;
      const size_t ebase = ((size_t)((bn * XTROWS + bh0 + ky) * XTCOLS + kx + colp) << 9)
                           + ks * 32 + sB;
      unsigned short* lp = &lds[sbuf][wid][0];
#pragma unroll
      for (int q = 0; q < 8; ++q)
        GLDS(xsrc + ebase + ((size_t)(((q >> 2) * XTCOLS + (q & 3) * 16)) << 9),
             lp + q * 512);
    }
  };

  stage(0, 0);
  __syncthreads();

  const int btile = 2 + ((wn >> 1) << 1);  /* 2 (B0h) or 4 (B1h); +1 is lo */

  int buf = 0;
  for (int ti = 0; ti < 144; ++ti) {
    if (ti < 143) stage(buf ^ 1, ti + 1);   /* issue next-step loads first */

    f16x8 ah[4], al[4], bhf[4], blf[4];
#pragma unroll
    for (int mi = 0; mi < 4; ++mi) {
      const int off = (((wm << 6) + (mi << 4) + fr) << 6) + slotr;
      ah[mi] = *(const f16x8*)((const char*)&lds[buf][0][0] + off);
      al[mi] = *(const f16x8*)((const char*)&lds[buf][1][0] + off);
    }
#pragma unroll
    for (int ni = 0; ni < 4; ++ni) {
      const int off = ((((wn & 1) << 6) + (ni << 4) + fr) << 6) + slotr;
      bhf[ni] = *(const f16x8*)((const char*)&lds[buf][btile][0] + off);
      blf[ni] = *(const f16x8*)((const char*)&lds[buf][btile + 1][0] + off);
    }
#pragma unroll
    for (int mi = 0; mi < 4; ++mi)
#pragma unroll
      for (int ni = 0; ni < 4; ++ni) {
        acc[mi][ni] = __builtin_amdgcn_mfma_f32_16x16x32_f16(ah[mi], bhf[ni], acc[mi][ni], 0, 0, 0);
        acc[mi][ni] = __builtin_amdgcn_mfma_f32_16x16x32_f16(ah[mi], blf[ni], acc[mi][ni], 0, 0, 0);
        acc[mi][ni] = __builtin_amdgcn_mfma_f32_16x16x32_f16(al[mi], bhf[ni], acc[mi][ni], 0, 0, 0);
      }
    __syncthreads();                        /* drains vmcnt(0): next buf ready */
    buf ^= 1;
  }

  const int nE  = (wn < 2) ? n0 : n1;
  const int h   = ((wn < 2) ? h00 : h10) + (wn & 1);
#pragma unroll
  for (int mi = 0; mi < 4; ++mi) {
    const int co = (cob << 7) + (wm << 6) + (mi << 4) + (fq << 2);
    const float4 bias = *(const float4*)&b1[co];
#pragma unroll
    for (int ni = 0; ni < 4; ++ni) {
      const int w = (ni << 4) + fr;
      float4 v;
      v.x = fmaxf(fmaf(acc[mi][ni][0], INV_SCALE, bias.x), 0.0f);
      v.y = fmaxf(fmaf(acc[mi][ni][1], INV_SCALE, bias.y), 0.0f);
      v.z = fmaxf(fmaf(acc[mi][ni][2], INV_SCALE, bias.z), 0.0f);
      v.w = fmaxf(fmaf(acc[mi][ni][3], INV_SCALE, bias.w), 0.0f);
      *(float4*)(feat + (((size_t)nE * HW + h * WF + w) << 9) + co) = v;
    }
  }
}

// ---------------------------------------------------------------------------
// K2: 1x1 heads + softmax-fg + box decode + clip + min-size filter.
// (identical numerics to validated r2 kernel; r7: float4 feat staging)
// ---------------------------------------------------------------------------
__global__ __launch_bounds__(256) void k_head(const float* __restrict__ feat,
                                              const float* __restrict__ WHT2,
                                              const float* __restrict__ bh,
                                              float* __restrict__ scores,
                                              float4* __restrict__ boxes) {
  __shared__ float fsh[16][512];
  __shared__ float vsh[16][64];
  const int t = threadIdx.x;
  const int wvid = t >> 6;
  const int o = t & 63;
  const int pos0 = blockIdx.x * 16;

  {
    const float4* fsrc = reinterpret_cast<const float4*>(feat + ((size_t)pos0 << 9));
    float4* fdst = reinterpret_cast<float4*>(&fsh[0][0]);
#pragma unroll
    for (int i = 0; i < 8; ++i) fdst[t + 256 * i] = fsrc[t + 256 * i];
  }
  __syncthreads();

  {
    const int p0 = wvid * 4;
    float a0 = 0.f, a1 = 0.f, a2 = 0.f, a3 = 0.f;
    const float4* wp = reinterpret_cast<const float4*>(WHT2);
    const float4* f0 = reinterpret_cast<const float4*>(&fsh[p0 + 0][0]);
    const float4* f1 = reinterpret_cast<const float4*>(&fsh[p0 + 1][0]);
    const float4* f2 = reinterpret_cast<const float4*>(&fsh[p0 + 2][0]);
    const float4* f3 = reinterpret_cast<const float4*>(&fsh[p0 + 3][0]);
#pragma unroll 4
    for (int c4 = 0; c4 < 128; ++c4) {
      float4 w4 = wp[c4 * 64 + o];
      float4 v;
      v = f0[c4];
      a0 = fmaf(w4.x, v.x, a0); a0 = fmaf(w4.y, v.y, a0);
      a0 = fmaf(w4.z, v.z, a0); a0 = fmaf(w4.w, v.w, a0);
      v = f1[c4];
      a1 = fmaf(w4.x, v.x, a1); a1 = fmaf(w4.y, v.y, a1);
      a1 = fmaf(w4.z, v.z, a1); a1 = fmaf(w4.w, v.w, a1);
      v = f2[c4];
      a2 = fmaf(w4.x, v.x, a2); a2 = fmaf(w4.y, v.y, a2);
      a2 = fmaf(w4.z, v.z, a2); a2 = fmaf(w4.w, v.w, a2);
      v = f3[c4];
      a3 = fmaf(w4.x, v.x, a3); a3 = fmaf(w4.y, v.y, a3);
      a3 = fmaf(w4.z, v.z, a3); a3 = fmaf(w4.w, v.w, a3);
    }
    float bv = bh[o];
    vsh[p0 + 0][o] = a0 + bv;
    vsh[p0 + 1][o] = a1 + bv;
    vsh[p0 + 2][o] = a2 + bv;
    vsh[p0 + 3][o] = a3 + bv;
  }
  __syncthreads();

  if (t < 144) {
    const int p2 = t / 9, a = t % 9;
    const int pos = pos0 + p2;
    const int n = pos / HW;
    const int r = pos - n * HW;
    const int ph = r >> 6;
    const int pw = r & 63;

    float l0 = vsh[p2][a * 2];
    float l1 = vsh[p2][a * 2 + 1];
    float m  = fmaxf(l0, l1);
    float e0 = (float)exp((double)__fsub_rn(l0, m));
    float e1 = (float)exp((double)__fsub_rn(l1, m));
    float fg = __fdiv_rn(e1, __fadd_rn(e0, e1));

    float d0 = vsh[p2][18 + a * 4 + 0];
    float d1 = vsh[p2][18 + a * 4 + 1];
    float d2 = vsh[p2][18 + a * 4 + 2];
    float d3 = vsh[p2][18 + a * 4 + 3];

    float sx = (float)(pw * 16);
    float sy = (float)(ph * 16);
    float ax1 = __fadd_rn(BASEA[a][0], sx);
    float ay1 = __fadd_rn(BASEA[a][1], sy);
    float ax2 = __fadd_rn(BASEA[a][2], sx);
    float ay2 = __fadd_rn(BASEA[a][3], sy);
    float aw = __fsub_rn(ax2, ax1);
    float ah = __fsub_rn(ay2, ay1);
    float acx = __fadd_rn(ax1, __fmul_rn(0.5f, aw));
    float acy = __fadd_rn(ay1, __fmul_rn(0.5f, ah));
    float cx = __fadd_rn(__fmul_rn(d0, aw), acx);
    float cy = __fadd_rn(__fmul_rn(d1, ah), acy);
    float pwd = __fmul_rn((float)exp((double)d2), aw);
    float phd = __fmul_rn((float)exp((double)d3), ah);
    float x1 = __fsub_rn(cx, __fmul_rn(0.5f, pwd));
    float y1 = __fsub_rn(cy, __fmul_rn(0.5f, phd));
    float x2 = __fadd_rn(cx, __fmul_rn(0.5f, pwd));
    float y2 = __fadd_rn(cy, __fmul_rn(0.5f, phd));
    x1 = fminf(fmaxf(x1, 0.0f), 1024.0f);
    x2 = fminf(fmaxf(x2, 0.0f), 1024.0f);
    y1 = fminf(fmaxf(y1, 0.0f), 800.0f);
    y2 = fminf(fmaxf(y2, 0.0f), 800.0f);
    float wsz = __fsub_rn(x2, x1);
    float hsz = __fsub_rn(y2, y1);
    float sc = (wsz >= 16.0f && hsz >= 16.0f) ? fg : -__builtin_huge_valf();

    const int idx = n * KPER + r * NA + a;
    scores[idx] = sc;
    boxes[idx] = make_float4(x1, y1, x2, y2);
  }
}

// ---------------------------------------------------------------------------
// K3 (merged topk + sort; r12: wave-private bitonic stages).  For j<=256 both
// elements of a compare-swap lie inside one wave's 512-elem segment (i and
// i|j differ below bit 9), waves are lockstep and LDS ops are ordered by the
// compiler -> no barrier needed for those stages.  Only j>=512 stages (10 of
// them) + per-k transitions barrier: ~23 barriers vs 91.  Identical network
// -> identical output.
// ---------------------------------------------------------------------------
__global__ __launch_bounds__(1024) void k_select(const float* __restrict__ scores,
                                                 const float4* __restrict__ boxes,
                                                 float4* __restrict__ sbox,
                                                 u64* __restrict__ valid) {
  __shared__ u64 sk[8192];
  __shared__ unsigned int whist[16][264];   /* per-wave, 264-stride staggers banks */
  __shared__ unsigned int histT[256];
  __shared__ unsigned int sh_selB, sh_ngt, sh_binc, sh_num;
  const int n = blockIdx.x;
  const int t = threadIdx.x;
  const int wv = t >> 6;
  const int ln = t & 63;
  const float* sc = scores + (size_t)n * KPER;
  const float4* sc4 = reinterpret_cast<const float4*>(sc);

  for (int e = t; e < 8192; e += 1024) sk[e] = 0ull;   /* pad + slots */

  unsigned int prefix = 0, prefMask = 0, ngt = 0, neq = 0;
  for (int shift = 24; shift >= 0; shift -= 8) {
    for (int e = t; e < 16 * 264; e += 1024) (&whist[0][0])[e] = 0u;
    __syncthreads();
    for (int i4 = t; i4 < KPER / 4; i4 += 1024) {
      const float4 v = sc4[i4];
      unsigned int u;
      u = ordf(v.x); if ((u & prefMask) == prefix) atomicAdd(&whist[wv][(u >> shift) & 255], 1u);
      u = ordf(v.y); if ((u & prefMask) == prefix) atomicAdd(&whist[wv][(u >> shift) & 255], 1u);
      u = ordf(v.z); if ((u & prefMask) == prefix) atomicAdd(&whist[wv][(u >> shift) & 255], 1u);
      u = ordf(v.w); if ((u & prefMask) == prefix) atomicAdd(&whist[wv][(u >> shift) & 255], 1u);
    }
    __syncthreads();
    if (t < 256) {
      unsigned int s = 0;
#pragma unroll
      for (int w = 0; w < 16; ++w) s += whist[w][t];
      histT[t] = s;
    }
    __syncthreads();
    if (t == 0) {
      unsigned int cnt = ngt;
      for (int b = 255; b >= 0; --b) {
        unsigned int c = histT[b];
        if (cnt + c >= (unsigned)PRE) { sh_selB = (unsigned)b; sh_ngt = cnt; sh_binc = c; break; }
        cnt += c;
      }
    }
    __syncthreads();
    prefix |= (sh_selB << shift);
    prefMask |= (0xFFu << shift);
    ngt = sh_ngt;
    neq = sh_binc;
    __syncthreads();
  }
  const unsigned int T = prefix;
  const unsigned int needed = (unsigned)PRE - ngt;
  unsigned int J = 0xFFFFFFFFu;
  if (needed < neq) {
    if (t < 256) histT[t] = 0;
    __syncthreads();
    for (int i = t; i < KPER; i += 1024)
      if (ordf(sc[i]) == T) atomicAdd(&histT[i >> 7], 1u);
    __syncthreads();
    if (t == 0) {
      unsigned int cnt = 0;
      for (int b = 0; b < 256; ++b) {
        unsigned int c = histT[b];
        if (cnt + c >= needed) { sh_selB = (unsigned)b; sh_ngt = needed - cnt; break; }
        cnt += c;
      }
    }
    __syncthreads();
    const unsigned int selH = sh_selB;
    const unsigned int needLow = sh_ngt;
    __syncthreads();
    if (t < 128) histT[t] = 0;
    __syncthreads();
    for (int i = t; i < KPER; i += 1024)
      if (ordf(sc[i]) == T && ((unsigned)(i >> 7)) == selH) atomicAdd(&histT[i & 127], 1u);
    __syncthreads();
    if (t == 0) {
      unsigned int cnt = 0;
      for (int b = 0; b < 128; ++b) {
        unsigned int c = histT[b];
        if (cnt + c >= needLow) { sh_selB = (selH << 7) | (unsigned)b; break; }
        cnt += c;
      }
    }
    __syncthreads();
    J = sh_selB;
  }

  if (t == 0) sh_num = 0;
  __syncthreads();
  for (int i4 = t; i4 < KPER / 4; i4 += 1024) {
    const float4 v = sc4[i4];
    const float vv[4] = {v.x, v.y, v.z, v.w};
#pragma unroll
    for (int c = 0; c < 4; ++c) {
      const int i = i4 * 4 + c;
      unsigned int u = ordf(vv[c]);
      bool in = (u > T) || (u == T && (unsigned)i <= J);
      if (in) {
        unsigned int p = atomicAdd(&sh_num, 1u);
        sk[p] = (((u64)u) << 32) | (u64)(~(unsigned int)i);
      }
    }
  }
  __syncthreads();

  /* bitonic sort descending, 8192 elems; wave-private stages for j<=256 */
  for (int k = 2; k <= 8192; k <<= 1) {
    for (int j = k >> 1; j >= 512; j >>= 1) {
      for (int p = t; p < 4096; p += 1024) {
        const int i = ((p & ~(j - 1)) << 1) | (p & (j - 1));
        const int ip = i | j;
        u64 a = sk[i], b = sk[ip];
        const bool desc = ((i & k) == 0);
        if ((a < b) == desc) { sk[i] = b; sk[ip] = a; }
      }
      __syncthreads();
    }
    const int j0 = (k >> 1 < 512) ? (k >> 1) : 256;
    for (int j = j0; j > 0; j >>= 1) {
      for (int q = ln; q < 256; q += 64) {
        const int p = wv * 256 + q;
        const int i = ((p & ~(j - 1)) << 1) | (p & (j - 1));
        const int ip = i | j;
        u64 a = sk[i], b = sk[ip];
        const bool desc = ((i & k) == 0);
        if ((a < b) == desc) { sk[i] = b; sk[ip] = a; }
      }
    }
    __syncthreads();
  }

  /* gather sorted boxes + valid bitmap */
  for (int e = t; e < NCAP; e += 1024) {
    float4 bx = make_float4(0.f, 0.f, 0.f, 0.f);
    if (e < PRE) {
      unsigned idx = ~(unsigned)(sk[e] & 0xFFFFFFFFull);
      bx = boxes[(size_t)n * KPER + idx];
    }
    sbox[(size_t)n * NCAP + e] = bx;
  }
  if (t < 128) {
    u64 w = 0;
    if (t < NW) {
      for (int b = 0; b < 64; ++b) {
        int e = t * 64 + b;
        if (e < PRE && ((sk[e] >> 32) > 0x007FFFFFull)) w |= 1ull << b;
      }
    }
    valid[n * 128 + t] = w;
  }
}

// ---------------------------------------------------------------------------
// K4b: IoU>=0.7 bitmask, UPPER TRIANGLE ONLY (jb >= ib).  (validated r4)
// ---------------------------------------------------------------------------
__global__ __launch_bounds__(64) void k_mask(const float4* __restrict__ sbox,
                                             u64* __restrict__ mask) {
  const int p = blockIdx.x;           /* 0..4464 */
  const int n = blockIdx.y;
  int ib = (int)((189.0 - sqrt(35721.0 - 8.0 * (double)p)) * 0.5);
  while (94 * (ib + 1) - (ib * (ib + 1)) / 2 <= p) ++ib;
  while (94 * ib - ((ib - 1) * ib) / 2 > p) --ib;
  const int jb = ib + (p - (94 * ib - ((ib - 1) * ib) / 2));

  const int r = threadIdx.x;
  const int i = ib * 64 + r;
  __shared__ float4 jbox[64];
  jbox[r] = sbox[(size_t)n * NCAP + jb * 64 + r];
  __syncthreads();
  const float4 pbx = sbox[(size_t)n * NCAP + i];
  const float pa = __fmul_rn(__fsub_rn(pbx.z, pbx.x), __fsub_rn(pbx.w, pbx.y));
  u64 word = 0;
#pragma unroll 8
  for (int b = 0; b < 64; ++b) {
    const float4 q = jbox[b];
    float ltx = fmaxf(pbx.x, q.x);
    float lty = fmaxf(pbx.y, q.y);
    float rbx = fminf(pbx.z, q.z);
    float rby = fminf(pbx.w, q.w);
    float wv = fmaxf(__fsub_rn(rbx, ltx), 0.0f);
    float hv = fmaxf(__fsub_rn(rby, lty), 0.0f);
    float inter = __fmul_rn(wv, hv);
    float a2 = __fmul_rn(__fsub_rn(q.z, q.x), __fsub_rn(q.w, q.y));
    float denom = __fadd_rn(__fsub_rn(__fadd_rn(pa, a2), inter), 1e-9f);
    float iou = __fdiv_rn(inter, denom);
    if (iou >= 0.7f) word |= (1ull << b);
  }
  mask[((size_t)(n * NCAP) + i) * NW + jb] = word;
}

// ---------------------------------------------------------------------------
// K4c (r12): streaming bit-scan, depth-2 group prefetch, TRIANGULAR loads:
// row i only has initialized words >= i>>6 (upper triangle); lanes whose two
// words fall entirely below that skip the load (OR of zeros = no-op; bits
// below a kept row's word index are never consulted -- r4 argument).  Halves
// the mask traffic.  Decision logic bit-identical to r4/r8.
// ---------------------------------------------------------------------------
__global__ __launch_bounds__(64) void k_scan(const u64* __restrict__ mask,
                                             const u64* __restrict__ valid,
                                             const float4* __restrict__ sbox,
                                             float* __restrict__ out) {
  const int n = blockIdx.x;
  const int lane = threadIdx.x;
  u64 s0 = 0, s1 = 0;
  const u64 v0 = valid[n * 128 + 2 * lane];
  const u64 v1 = valid[n * 128 + 2 * lane + 1];
  const u64* mrow = mask + (size_t)n * NCAP * NW;
  __shared__ int keep_list[POST];
  int kept = 0;

  auto ldrow = [&](int i) -> ulonglong2 {
    ulonglong2 q; q.x = 0ull; q.y = 0ull;
    if (lane < 47 && (2 * lane + 1) >= (i >> 6))
      q = reinterpret_cast<const ulonglong2*>(mrow + (size_t)i * NW)[lane];
    return q;
  };

  const int NG = PRE / 16;   /* 375 */
  ulonglong2 c0[16], c1[16], c2[16];
#pragma unroll
  for (int r = 0; r < 16; ++r) c0[r] = ldrow(r);
#pragma unroll
  for (int r = 0; r < 16; ++r) c1[r] = ldrow(16 + r);

  for (int g = 0; g < NG; ++g) {
    if (kept >= POST) break;
    if (g + 2 < NG) {
#pragma unroll
      for (int r = 0; r < 16; ++r)
        c2[r] = ldrow((g + 2) * 16 + r);
    }
#pragma unroll
    for (int r = 0; r < 16; ++r) {
      if (kept < POST) {
        const int i = g * 16 + r;
        const int w = i >> 6;
        const u64 avail = (w & 1) ? (v1 & ~s1) : (v0 & ~s0);
        const unsigned h32 = (unsigned)(avail >> (i & 32));
        const unsigned wrd = __shfl(h32, w >> 1, 64);
        if ((wrd >> (i & 31)) & 1u) {
          if (lane == 0) keep_list[kept] = i;
          ++kept;
          s0 |= c0[r].x;
          s1 |= c0[r].y;
        }
      }
    }
#pragma unroll
    for (int r = 0; r < 16; ++r) { c0[r] = c1[r]; c1[r] = c2[r]; }
  }
  __syncthreads();

  for (int it = lane; it < POST; it += 64) {
    const int cand = (it < kept) ? keep_list[it] : 0;
    const float4 b = sbox[(size_t)n * NCAP + cand];
    float* orow = out + ((size_t)n * POST + it) * 4;
    orow[0] = b.x; orow[1] = b.y; orow[2] = b.z; orow[3] = b.w;
    out[(size_t)NIMG * POST * 4 + (size_t)n * POST + it] = (float)n;
  }
}

extern "C" void kernel_launch(void* const* d_in, const int* in_sizes, int n_in,
                              void* d_out, int out_size, void* d_ws, size_t ws_size,
                              hipStream_t stream) {
  const float* x    = (const float*)d_in[0];
  const float* w1   = (const float*)d_in[1];
  const float* b1   = (const float*)d_in[2];
  const float* wcls = (const float*)d_in[3];
  const float* bcls = (const float*)d_in[4];
  const float* wbb  = (const float*)d_in[5];
  const float* bbb  = (const float*)d_in[6];
  float* out = (float*)d_out;

  char* ws = (char*)d_ws;
  size_t off = 0;
  float* feat = (float*)(ws + off);               off += (size_t)NIMG * HW * CIN * 4;
  float* scores = (float*)(ws + off);             off += (size_t)NIMG * KPER * 4;
  float4* boxes = (float4*)(ws + off);            off += (size_t)NIMG * KPER * 16;
  float4* sbox = (float4*)(ws + off);             off += (size_t)NIMG * NCAP * 16;
  u64* valid = (u64*)(ws + off);                  off += (size_t)NIMG * 128 * 8;
  u64* mask = (u64*)(ws + off);                   off += (size_t)NIMG * NCAP * NW * 8;
  float* WHT2 = (float*)(ws + off);               off += (size_t)WHT_ELEMS * 4;
  float* bh   = (float*)(ws + off);               off += 256;
  unsigned short* xTh = (unsigned short*)(ws + off); off += XT_BYTES;
  unsigned short* xTl = (unsigned short*)(ws + off); off += XT_BYTES;
  unsigned short* wpk = (unsigned short*)(ws + off); off += WPK_ELEMS * 2;

  k_prep_all<<<PB_TOT, 256, 0, stream>>>((const float4*)x, w1, wcls, bcls, wbb, bbb,
                                         xTh, xTl, wpk, WHT2, bh);
  k_convmfma<<<400, 512, 0, stream>>>(xTh, xTl, wpk, b1, feat);
  k_head<<<(NIMG * HW) / 16, 256, 0, stream>>>(feat, WHT2, bh, scores, boxes);
  k_select<<<NIMG, 1024, 0, stream>>>(scores, boxes, sbox, valid);
  k_mask<<<dim3(NTRI, NIMG), 64, 0, stream>>>(sbox, mask);
  k_scan<<<NIMG, 64, 0, stream>>>(mask, valid, sbox, out);
}